// Round 6
// baseline (328.248 us; speedup 1.0000x reference)
//
#include <hip/hip_runtime.h>

typedef float f32x4 __attribute__((ext_vector_type(4)));
typedef short s16x8 __attribute__((ext_vector_type(8)));

#define DEV __device__ __forceinline__

DEV short f2bf(float f) {
    union { float f; unsigned u; } v; v.f = f;
    unsigned r = v.u + 0x7fffu + ((v.u >> 16) & 1u);
    return (short)(r >> 16);
}
DEV float bf2f(short s) {
    union { unsigned u; float f; } v; v.u = ((unsigned)(unsigned short)s) << 16;
    return v.f;
}

// B=2, Q=K=2048, D=512, H=8, hd=64. KV padded: 2048 real + 1 zero-attn + 31 pad = 2080
#define SEQ    2048
#define DMODEL 512
#define KPAD   2080
#define NROWS  32768   /* B*H*SEQ flash output rows */

// ws layout (bytes). qn|kn|vn contiguous (single QKV GEMM A), weights contiguous.
#define OFF_QN   0ull            /* 4096*512*2  = 4,194,304 */
#define OFF_KN   4194304ull      /* 4160*512*2  = 4,259,840 */
#define OFF_VN   8454144ull      /* 4160*512*2  -> ends 12,713,984 */
#define OFF_QH   12845056ull     /* 4,194,304 */
#define OFF_KH   17039360ull     /* 4,259,840 -> ends 21,299,200 */
#define OFF_VH   21364736ull     /* vhp 4,259,840 -> ends 25,624,576 */
#define OFF_VHT  25690112ull     /* 4,259,840 -> ends 29,949,952 */
#define OFF_AV   29949952ull     /* 4,194,304 */
#define OFF_WQT  34144256ull     /* WqT|WkT|WvT|WoT|gWT = 4*524,288 + 1,048,576 */
#define WS_NEEDED 37289984ull
// aliased (lifetimes disjoint):
#define OFF_ON   0ull            /* flash partials bf16 [2][32768][64] = 8,388,608 over qn+kn (dead post-qkv) */
#define OFF_ML   8388608ull      /* (m,l) f32 [2][32768][2] = 524,288 -> ends 8,912,896 (kn/vn, dead post-qkv) */
#define OFF_KB   29949952ull     /* key bias f32 2*2080*4 = 16,640 over av region (first written by merge) */
#define OFF_AP   17039360ull     /* attn_proj f32 8,388,608 over kh+vhp (dead post-flash/transpose) */

// ---------------------------------------------------------------- fused LayerNorm+cast (q,k,v)
__global__ __launch_bounds__(256) void ln_all(
    const float* __restrict__ q, const float* __restrict__ k, const float* __restrict__ v,
    const float* __restrict__ qg, const float* __restrict__ qb,
    const float* __restrict__ kg, const float* __restrict__ kb2,
    const float* __restrict__ vg, const float* __restrict__ vb,
    short* __restrict__ qn, short* __restrict__ kn, short* __restrict__ vn)
{
    int bid = blockIdx.x;
    const float *in, *gamma, *beta; short* out; int Sreal, Spad;
    if (bid < 1024)      { in=q; gamma=qg; beta=qb;  out=qn; Sreal=SEQ; Spad=SEQ;  }
    else if (bid < 2064) { bid-=1024; in=k; gamma=kg; beta=kb2; out=kn; Sreal=SEQ; Spad=KPAD; }
    else                 { bid-=2064; in=v; gamma=vg; beta=vb;  out=vn; Sreal=SEQ; Spad=KPAD; }

    int w = threadIdx.x >> 6, l = threadIdx.x & 63;
    int r = bid * 4 + w;
    short* op = out + (size_t)r * DMODEL + l * 8;
    s16x8 o = {0,0,0,0,0,0,0,0};
    if (r >= 2 * Spad) { *(s16x8*)op = o; return; }
    int b = r / Spad, j = r - b * Spad;
    if (j >= Sreal) {
        if (j == Sreal) {
            f32x4 b0 = *(const f32x4*)(beta + l*8);
            f32x4 b1 = *(const f32x4*)(beta + l*8 + 4);
            #pragma unroll
            for (int t=0;t<4;t++){ o[t]=f2bf(b0[t]); o[t+4]=f2bf(b1[t]); }
        }
        *(s16x8*)op = o; return;
    }
    const float* ip = in + ((size_t)b * Sreal + j) * DMODEL + l * 8;
    f32x4 x0 = *(const f32x4*)ip;
    f32x4 x1 = *(const f32x4*)(ip + 4);
    float s = x0[0]+x0[1]+x0[2]+x0[3]+x1[0]+x1[1]+x1[2]+x1[3];
    #pragma unroll
    for (int off=1; off<64; off<<=1) s += __shfl_xor(s, off);
    float mean = s * (1.0f/512.0f);
    float vs = 0.f;
    #pragma unroll
    for (int t=0;t<4;t++){ float d0=x0[t]-mean, d1=x1[t]-mean; vs += d0*d0 + d1*d1; }
    #pragma unroll
    for (int off=1; off<64; off<<=1) vs += __shfl_xor(vs, off);
    float rstd = rsqrtf(vs * (1.0f/512.0f) + 1e-5f);
    f32x4 g0 = *(const f32x4*)(gamma + l*8), g1 = *(const f32x4*)(gamma + l*8 + 4);
    f32x4 b0 = *(const f32x4*)(beta + l*8),  b1 = *(const f32x4*)(beta + l*8 + 4);
    #pragma unroll
    for (int t=0;t<4;t++){
        o[t]   = f2bf((x0[t]-mean)*rstd*g0[t] + b0[t]);
        o[t+4] = f2bf((x1[t]-mean)*rstd*g1[t] + b1[t]);
    }
    *(s16x8*)op = o;
}

// ---------------------------------------------------------------- all weights transpose+cast + kbias
__global__ __launch_bounds__(256) void wt_all(
    const float* __restrict__ Wq, const float* __restrict__ Wk,
    const float* __restrict__ Wv, const float* __restrict__ Wo,
    const float* __restrict__ gW, short* __restrict__ WT,
    const int* __restrict__ km, float* __restrict__ kbias)
{
    int bid = blockIdx.x;
    if (bid >= 1536) {
        int i = (bid - 1536) * 256 + threadIdx.x;
        if (i >= 2 * KPAD) return;
        int b = i / KPAD, j = i - b * KPAD;
        float v;
        if (j < SEQ)       v = km[b*SEQ + j] ? 0.0f : -1e30f;
        else if (j == SEQ) v = 0.0f;     // zero-attn slot (mask bit 1)
        else               v = -1e30f;   // pad rows
        kbias[i] = v;
        return;
    }
    const float* in; short* out; int K;
    if (bid < 1024) {
        int wsel = bid >> 8;
        in = (wsel==0) ? Wq : (wsel==1) ? Wk : (wsel==2) ? Wv : Wo;
        out = WT + (size_t)wsel * 262144;
        K = 512; bid &= 255;
    } else {
        in = gW; out = WT + 1048576; K = 1024; bid -= 1024;
    }
    __shared__ float t[32][33];
    int bx = bid & 15, by = bid >> 4;   // N=512 always -> 16 col tiles
    int n0 = bx * 32, k0 = by * 32;
    int tx = threadIdx.x & 31, ty = threadIdx.x >> 5;
    #pragma unroll
    for (int i=0;i<4;i++)
        t[ty + i*8][tx] = in[(size_t)(k0 + ty + i*8) * 512 + n0 + tx];
    __syncthreads();
    #pragma unroll
    for (int i=0;i<4;i++)
        out[(size_t)(n0 + ty + i*8) * K + k0 + tx] = f2bf(t[tx][ty + i*8]);
}

// ---------------------------------------------------------------- fused QKV projection GEMM
// A = qn|kn|vn contiguous (12416,512) bf16; B = WqkvT (3 segs of (512,512)).
// Coalesced row writes: seg0 -> qh, seg1 -> khp, seg2 -> vhp.
__global__ __launch_bounds__(256) void qkv_gemm(
    const short* __restrict__ A, const short* __restrict__ WT,
    short* __restrict__ qh, short* __restrict__ khp, short* __restrict__ vhp)
{
    __shared__ short As[64*64];
    __shared__ short Bs[64*64];
    int tid = threadIdx.x;
    int w = tid >> 6, l = tid & 63;
    int lr = l & 15, lg = l >> 4;
    int tm = blockIdx.x >> 3, tn = blockIdx.x & 7;
    int seg = (tm < 64) ? 0 : (tm < 129) ? 1 : 2;
    const short* Bt = WT + (size_t)seg * 262144;
    int wm = w >> 1, wn = w & 1;
    int srow = tid >> 3, sslot = tid & 7;

    f32x4 acc[2][2];
    #pragma unroll
    for (int m=0;m<2;m++)
        #pragma unroll
        for (int n=0;n<2;n++) acc[m][n] = (f32x4){0.f,0.f,0.f,0.f};

    for (int k0 = 0; k0 < 512; k0 += 64) {
        #pragma unroll
        for (int i=0;i<2;i++){
            int row = i*32 + srow;
            int gslot = sslot ^ (row & 7);
            const short* ga = A  + (size_t)(tm*64 + row) * 512 + k0 + gslot*8;
            const short* gb = Bt + (size_t)(tn*64 + row) * 512 + k0 + gslot*8;
            short* la = As + (i*256 + w*64) * 8;
            short* lb = Bs + (i*256 + w*64) * 8;
            __builtin_amdgcn_global_load_lds((const __attribute__((address_space(1))) void*)ga,
                                             (__attribute__((address_space(3))) void*)la, 16, 0, 0);
            __builtin_amdgcn_global_load_lds((const __attribute__((address_space(1))) void*)gb,
                                             (__attribute__((address_space(3))) void*)lb, 16, 0, 0);
        }
        __syncthreads();
        #pragma unroll
        for (int s=0;s<2;s++){
            s16x8 af[2], bfr[2];
            #pragma unroll
            for (int m=0;m<2;m++){
                int row = wm*32 + m*16 + lr;
                int slot = (s*4 + lg) ^ (row & 7);
                af[m] = *(const s16x8*)(As + row*64 + slot*8);
            }
            #pragma unroll
            for (int n=0;n<2;n++){
                int row = wn*32 + n*16 + lr;
                int slot = (s*4 + lg) ^ (row & 7);
                bfr[n] = *(const s16x8*)(Bs + row*64 + slot*8);
            }
            #pragma unroll
            for (int m=0;m<2;m++)
                #pragma unroll
                for (int n=0;n<2;n++)
                    acc[m][n] = __builtin_amdgcn_mfma_f32_16x16x32_bf16(af[m], bfr[n], acc[m][n], 0, 0, 0);
        }
        __syncthreads();
    }

    #pragma unroll
    for (int n=0;n<2;n++){
        int col = tn*64 + wn*32 + n*16 + lr;
        #pragma unroll
        for (int m=0;m<2;m++){
            #pragma unroll
            for (int j=0;j<4;j++){
                int row = tm*64 + wm*32 + m*16 + lg*4 + j;
                short v = f2bf(acc[m][n][j]);
                if (seg == 0)      qh [(size_t)row*512 + col] = v;
                else if (seg == 1) khp[(size_t)(row - 4096)*512 + col] = v;
                else               vhp[(size_t)(row - 8256)*512 + col] = v;
            }
        }
    }
}

// ---------------------------------------------------------------- vhp -> vhT[b][h][64][KPAD]
__global__ __launch_bounds__(256) void transpose_v(
    const short* __restrict__ vh, short* __restrict__ vhT)
{
    __shared__ short t[64][72];
    int tid = threadIdx.x, bid = blockIdx.x;
    int kt = bid % 33; int hh = (bid / 33) & 7; int b = bid / (33*8);
    int k0 = kt * 64;
    int rr = tid >> 3, c8 = (tid & 7) * 8;
    #pragma unroll
    for (int p=0;p<2;p++){
        int kr = p*32 + rr;
        int gk = k0 + kr;
        s16x8 v = {0,0,0,0,0,0,0,0};
        if (gk < KPAD) v = *(const s16x8*)(vh + (size_t)(b*KPAD + gk)*DMODEL + hh*64 + c8);
        *(s16x8*)&t[kr][c8] = v;
    }
    __syncthreads();
    #pragma unroll
    for (int p=0;p<2;p++){
        int dr = p*32 + rr;
        if (k0 + c8 < KPAD){
            s16x8 o;
            #pragma unroll
            for (int j2=0;j2<8;j2++) o[j2] = t[c8+j2][dr];
            *(s16x8*)(vhT + ((size_t)(b*8 + hh)*64 + dr)*KPAD + k0 + c8) = o;
        }
    }
}

// ---------------------------------------------------------------- bf16 GEMM 64x64 tile (Wo), f32 out
__global__ __launch_bounds__(256) void gemm64f(
    const short* __restrict__ A, const short* __restrict__ Bt,
    float* __restrict__ C, int M, int N, int K)
{
    __shared__ short As[64*64];
    __shared__ short Bs[64*64];
    int tid = threadIdx.x;
    int w = tid >> 6, l = tid & 63;
    int lr = l & 15, lg = l >> 4;
    int nt = N >> 6;
    int tm = blockIdx.x / nt, tn = blockIdx.x - tm * nt;
    int wm = w >> 1, wn = w & 1;
    int srow = tid >> 3, sslot = tid & 7;

    f32x4 acc[2][2];
    #pragma unroll
    for (int m=0;m<2;m++)
        #pragma unroll
        for (int n=0;n<2;n++) acc[m][n] = (f32x4){0.f,0.f,0.f,0.f};

    for (int k0 = 0; k0 < K; k0 += 64) {
        #pragma unroll
        for (int i=0;i<2;i++){
            int row = i*32 + srow;
            int gslot = sslot ^ (row & 7);
            const short* ga = A  + (size_t)(tm*64 + row) * K + k0 + gslot*8;
            const short* gb = Bt + (size_t)(tn*64 + row) * K + k0 + gslot*8;
            short* la = As + (i*256 + w*64) * 8;
            short* lb = Bs + (i*256 + w*64) * 8;
            __builtin_amdgcn_global_load_lds((const __attribute__((address_space(1))) void*)ga,
                                             (__attribute__((address_space(3))) void*)la, 16, 0, 0);
            __builtin_amdgcn_global_load_lds((const __attribute__((address_space(1))) void*)gb,
                                             (__attribute__((address_space(3))) void*)lb, 16, 0, 0);
        }
        __syncthreads();
        #pragma unroll
        for (int s=0;s<2;s++){
            s16x8 af[2], bfr[2];
            #pragma unroll
            for (int m=0;m<2;m++){
                int row = wm*32 + m*16 + lr;
                int slot = (s*4 + lg) ^ (row & 7);
                af[m] = *(const s16x8*)(As + row*64 + slot*8);
            }
            #pragma unroll
            for (int n=0;n<2;n++){
                int row = wn*32 + n*16 + lr;
                int slot = (s*4 + lg) ^ (row & 7);
                bfr[n] = *(const s16x8*)(Bs + row*64 + slot*8);
            }
            #pragma unroll
            for (int m=0;m<2;m++)
                #pragma unroll
                for (int n=0;n<2;n++)
                    acc[m][n] = __builtin_amdgcn_mfma_f32_16x16x32_bf16(af[m], bfr[n], acc[m][n], 0, 0, 0);
        }
        __syncthreads();
    }

    #pragma unroll
    for (int n=0;n<2;n++){
        int col = tn*64 + wn*32 + n*16 + lr;
        #pragma unroll
        for (int m=0;m<2;m++){
            #pragma unroll
            for (int j=0;j<4;j++){
                int row = tm*64 + wm*32 + m*16 + lg*4 + j;
                C[(size_t)row*N + col] = acc[m][n][j];
            }
        }
    }
}

// ---------------------------------------------------------------- gate GEMM (fused concat + sigmoid combine)
__global__ __launch_bounds__(256) void gate_gemm(
    const float* __restrict__ query, const float* __restrict__ ap,
    const short* __restrict__ gWT, const float* __restrict__ gB,
    float* __restrict__ out)
{
    __shared__ short As[64*64];
    __shared__ short Bs[64*64];
    int tid = threadIdx.x;
    int w = tid >> 6, l = tid & 63;
    int lr = l & 15, lg = l >> 4;
    int tm = blockIdx.x >> 3, tn = blockIdx.x & 7;
    int wm = w >> 1, wn = w & 1;
    int srow = tid >> 3, sslot = tid & 7;

    f32x4 acc[2][2];
    #pragma unroll
    for (int m=0;m<2;m++)
        #pragma unroll
        for (int n=0;n<2;n++) acc[m][n] = (f32x4){0.f,0.f,0.f,0.f};

    for (int k0 = 0; k0 < 1024; k0 += 64) {
        const float* src = (k0 < 512) ? query : ap;
        int csub = (k0 < 512) ? k0 : k0 - 512;
        #pragma unroll
        for (int i=0;i<2;i++){
            int row = i*32 + srow;
            const float* gp = src + (size_t)(tm*64 + row) * 512 + csub + sslot*8;
            f32x4 a0 = *(const f32x4*)gp;
            f32x4 a1 = *(const f32x4*)(gp + 4);
            s16x8 o;
            #pragma unroll
            for (int t=0;t<4;t++){ o[t] = f2bf(a0[t]); o[t+4] = f2bf(a1[t]); }
            int slot = sslot ^ (row & 7);
            *(s16x8*)(As + row*64 + slot*8) = o;
            int gslot = sslot ^ (row & 7);
            const short* gb = gWT + (size_t)(tn*64 + row) * 1024 + k0 + gslot*8;
            short* lb = Bs + (i*256 + w*64) * 8;
            __builtin_amdgcn_global_load_lds((const __attribute__((address_space(1))) void*)gb,
                                             (__attribute__((address_space(3))) void*)lb, 16, 0, 0);
        }
        __syncthreads();
        #pragma unroll
        for (int s=0;s<2;s++){
            s16x8 af[2], bfr[2];
            #pragma unroll
            for (int m=0;m<2;m++){
                int row = wm*32 + m*16 + lr;
                int slot = (s*4 + lg) ^ (row & 7);
                af[m] = *(const s16x8*)(As + row*64 + slot*8);
            }
            #pragma unroll
            for (int n=0;n<2;n++){
                int row = wn*32 + n*16 + lr;
                int slot = (s*4 + lg) ^ (row & 7);
                bfr[n] = *(const s16x8*)(Bs + row*64 + slot*8);
            }
            #pragma unroll
            for (int m=0;m<2;m++)
                #pragma unroll
                for (int n=0;n<2;n++)
                    acc[m][n] = __builtin_amdgcn_mfma_f32_16x16x32_bf16(af[m], bfr[n], acc[m][n], 0, 0, 0);
        }
        __syncthreads();
    }

    #pragma unroll
    for (int n=0;n<2;n++){
        int col = tn*64 + wn*32 + n*16 + lr;
        float badd = gB[col];
        #pragma unroll
        for (int m=0;m<2;m++){
            #pragma unroll
            for (int j=0;j<4;j++){
                int row = tm*64 + wm*32 + m*16 + lg*4 + j;
                size_t idx = (size_t)row*512 + col;
                float g = 1.0f / (1.0f + __expf(-(acc[m][n][j] + badd)));
                float q = query[idx], a = ap[idx];
                out[idx] = q + g*q + (1.0f - g)*a;
            }
        }
    }
}

// ---------------------------------------------------------------- flash attention, split-KV 2-way
// bid = [qblk:5][split:1][b:1][h:3] -> bid%8 == h: each XCD sees ONE head's K/V
// (both batches) = 1.06 MB -> L2-resident. Early-K + early-V register prefetch.
__global__ __launch_bounds__(256, 4) void flash_kernel(
    const short* __restrict__ qh, const short* __restrict__ kh,
    const short* __restrict__ vhT, const float* __restrict__ kbias,
    short* __restrict__ On, float* __restrict__ ml)
{
    __shared__ short plds[4][16*72];
    int tid = threadIdx.x;
    int w = tid >> 6, l = tid & 63;
    int bid = blockIdx.x;
    int b = (bid >> 3) & 1;
    int h = bid & 7;
    int split = (bid >> 4) & 1;
    int q0 = ((bid >> 5) * 4 + w) << 4;
    int cl = l & 15, rg = l >> 4;

    const short* qp = qh + ((size_t)(b*SEQ + q0 + cl))*DMODEL + h*64 + rg*8;
    s16x8 qf0 = *(const s16x8*)qp;
    s16x8 qf1 = *(const s16x8*)(qp + 32);

    f32x4 O[4];
    float mrow[4], lsum[4];
    #pragma unroll
    for (int n=0;n<4;n++) O[n] = (f32x4){0.f,0.f,0.f,0.f};
    #pragma unroll
    for (int j=0;j<4;j++){ mrow[j] = -1e30f; lsum[j] = 0.f; }

    const short* khb = kh + (size_t)b*KPAD*DMODEL + h*64;
    const short* vtb = vhT + (size_t)(b*8 + h)*64*KPAD;
    const float* kbb = kbias + b*KPAD;
    short* pl = plds[w];

    int kc0 = split * 16, kcN = kc0 + 16;

    // preload K fragments for first chunk
    s16x8 kf[8];
    #pragma unroll
    for (int nh=0; nh<4; ++nh){
        const short* kp = khb + (size_t)(kc0*64 + nh*16 + cl)*DMODEL + rg*8;
        kf[nh*2]   = *(const s16x8*)kp;
        kf[nh*2+1] = *(const s16x8*)(kp + 32);
    }

    for (int kc = kc0; kc < kcN; ++kc) {
        int k0 = kc * 64;
        float sv[4][4];
        #pragma unroll
        for (int nh=0; nh<4; ++nh) {
            f32x4 z = (f32x4){0.f,0.f,0.f,0.f};
            z = __builtin_amdgcn_mfma_f32_16x16x32_bf16(qf0, kf[nh*2],   z, 0, 0, 0);
            z = __builtin_amdgcn_mfma_f32_16x16x32_bf16(qf1, kf[nh*2+1], z, 0, 0, 0);
            float bias = kbb[k0 + nh*16 + cl];
            #pragma unroll
            for (int j=0;j<4;j++) sv[nh][j] = fmaf(z[j], 0.125f, bias);
        }
        float ml4[4];
        #pragma unroll
        for (int j=0;j<4;j++)
            ml4[j] = fmaxf(fmaxf(sv[0][j], sv[1][j]), fmaxf(sv[2][j], sv[3][j]));
        #pragma unroll
        for (int off=1; off<16; off<<=1){
            #pragma unroll
            for (int j=0;j<4;j++) ml4[j] = fmaxf(ml4[j], __shfl_xor(ml4[j], off));
        }
        bool need = (ml4[0] > mrow[0]+8.f) || (ml4[1] > mrow[1]+8.f) ||
                    (ml4[2] > mrow[2]+8.f) || (ml4[3] > mrow[3]+8.f);
        if (__any(need)) {
            #pragma unroll
            for (int j=0;j<4;j++){
                float mn = fmaxf(mrow[j], ml4[j]);
                float sc = __expf(mrow[j] - mn);
                mrow[j] = mn; lsum[j] *= sc;
                #pragma unroll
                for (int n=0;n<4;n++) O[n][j] *= sc;
            }
        }
        float ps[4] = {0.f,0.f,0.f,0.f};
        #pragma unroll
        for (int nh=0; nh<4; ++nh){
            #pragma unroll
            for (int j=0;j<4;j++){
                float p = __expf(sv[nh][j] - mrow[j]);
                ps[j] += p;
                pl[(rg*4 + j)*72 + nh*16 + cl] = f2bf(p);
            }
        }
        // early-V: issue V loads under the sum-reduce + lds reads
        s16x8 vf[8];
        #pragma unroll
        for (int n=0;n<4;n++){
            vf[n*2]   = *(const s16x8*)(vtb + (size_t)(n*16 + cl)*KPAD + k0 + rg*8);
            vf[n*2+1] = *(const s16x8*)(vtb + (size_t)(n*16 + cl)*KPAD + k0 + 32 + rg*8);
        }
        // early-K: prefetch next chunk's K fragments (hidden under shuffles + PV)
        if (kc + 1 < kcN) {
            #pragma unroll
            for (int nh=0; nh<4; ++nh){
                const short* kp = khb + (size_t)((k0+64) + nh*16 + cl)*DMODEL + rg*8;
                kf[nh*2]   = *(const s16x8*)kp;
                kf[nh*2+1] = *(const s16x8*)(kp + 32);
            }
        }
        #pragma unroll
        for (int off=1; off<16; off<<=1){
            #pragma unroll
            for (int j=0;j<4;j++) ps[j] += __shfl_xor(ps[j], off);
        }
        #pragma unroll
        for (int j=0;j<4;j++) lsum[j] += ps[j];

        s16x8 pa0 = *(const s16x8*)(pl + cl*72 + rg*8);
        s16x8 pa1 = *(const s16x8*)(pl + cl*72 + 32 + rg*8);
        __builtin_amdgcn_s_setprio(1);
        #pragma unroll
        for (int n=0;n<4;n++){
            O[n] = __builtin_amdgcn_mfma_f32_16x16x32_bf16(pa0, vf[n*2],   O[n], 0, 0, 0);
            O[n] = __builtin_amdgcn_mfma_f32_16x16x32_bf16(pa1, vf[n*2+1], O[n], 0, 0, 0);
        }
        __builtin_amdgcn_s_setprio(0);
    }

    if (split) {  // tail: keys 2048..2079
        int k0 = 2048;
        float sv[2][4];
        #pragma unroll
        for (int nh=0; nh<2; ++nh) {
            const short* kp = khb + (size_t)(k0 + nh*16 + cl)*DMODEL + rg*8;
            s16x8 ka = *(const s16x8*)kp;
            s16x8 kb2 = *(const s16x8*)(kp + 32);
            f32x4 z = (f32x4){0.f,0.f,0.f,0.f};
            z = __builtin_amdgcn_mfma_f32_16x16x32_bf16(qf0, ka,  z, 0, 0, 0);
            z = __builtin_amdgcn_mfma_f32_16x16x32_bf16(qf1, kb2, z, 0, 0, 0);
            float bias = kbb[k0 + nh*16 + cl];
            #pragma unroll
            for (int j=0;j<4;j++) sv[nh][j] = fmaf(z[j], 0.125f, bias);
        }
        float ml4[4];
        #pragma unroll
        for (int j=0;j<4;j++) ml4[j] = fmaxf(sv[0][j], sv[1][j]);
        #pragma unroll
        for (int off=1; off<16; off<<=1){
            #pragma unroll
            for (int j=0;j<4;j++) ml4[j] = fmaxf(ml4[j], __shfl_xor(ml4[j], off));
        }
        bool need = (ml4[0] > mrow[0]+8.f) || (ml4[1] > mrow[1]+8.f) ||
                    (ml4[2] > mrow[2]+8.f) || (ml4[3] > mrow[3]+8.f);
        if (__any(need)) {
            #pragma unroll
            for (int j=0;j<4;j++){
                float mn = fmaxf(mrow[j], ml4[j]);
                float sc = __expf(mrow[j] - mn);
                mrow[j] = mn; lsum[j] *= sc;
                #pragma unroll
                for (int n=0;n<4;n++) O[n][j] *= sc;
            }
        }
        float ps[4] = {0.f,0.f,0.f,0.f};
        #pragma unroll
        for (int nh=0; nh<2; ++nh){
            #pragma unroll
            for (int j=0;j<4;j++){
                float p = __expf(sv[nh][j] - mrow[j]);
                ps[j] += p;
                pl[(rg*4 + j)*72 + nh*16 + cl] = f2bf(p);
            }
        }
        s16x8 vf[4];
        #pragma unroll
        for (int n=0;n<4;n++)
            vf[n] = *(const s16x8*)(vtb + (size_t)(n*16 + cl)*KPAD + k0 + rg*8);
        #pragma unroll
        for (int off=1; off<16; off<<=1){
            #pragma unroll
            for (int j=0;j<4;j++) ps[j] += __shfl_xor(ps[j], off);
        }
        #pragma unroll
        for (int j=0;j<4;j++) lsum[j] += ps[j];

        s16x8 pa0 = *(const s16x8*)(pl + cl*72 + rg*8);
        __builtin_amdgcn_s_setprio(1);
        #pragma unroll
        for (int n=0;n<4;n++)
            O[n] = __builtin_amdgcn_mfma_f32_16x16x32_bf16(pa0, vf[n], O[n], 0, 0, 0);
        __builtin_amdgcn_s_setprio(0);
    }

    // store normalized partial + (m, l)
    int rbase = ((b*8 + h) << 11) + q0;
    #pragma unroll
    for (int j=0;j<4;j++){
        int r = rbase + rg*4 + j;
        float invl = 1.0f / lsum[j];
        #pragma unroll
        for (int n=0;n<4;n++)
            On[((size_t)split*NROWS + r)*64 + n*16 + cl] = f2bf(O[n][j] * invl);
        if (cl == 0){
            ml[((size_t)split*NROWS + r)*2    ] = mrow[j];
            ml[((size_t)split*NROWS + r)*2 + 1] = lsum[j];
        }
    }
}

// ---------------------------------------------------------------- merge split-KV partials -> av bf16
__global__ __launch_bounds__(256) void merge_kernel(
    const short* __restrict__ On, const float* __restrict__ ml,
    const int* __restrict__ qmask, short* __restrict__ av)
{
    int tid = threadIdx.x;
    int r = blockIdx.x * 32 + (tid >> 3);
    int d8 = (tid & 7) * 8;
    float m1 = ml[(size_t)r*2], l1 = ml[(size_t)r*2 + 1];
    float m2 = ml[((size_t)NROWS + r)*2], l2 = ml[((size_t)NROWS + r)*2 + 1];
    float m = fmaxf(m1, m2);
    float w1 = l1 * __expf(m1 - m), w2 = l2 * __expf(m2 - m);
    int qrow = r & 2047, bh = r >> 11, h = bh & 7, b = bh >> 3;
    int qm = qmask[b*SEQ + qrow];
    float inv = qm ? 1.0f / (w1 + w2) : 0.0f;
    w1 *= inv; w2 *= inv;
    s16x8 o1 = *(const s16x8*)(On + (size_t)r*64 + d8);
    s16x8 o2 = *(const s16x8*)(On + ((size_t)NROWS + r)*64 + d8);
    s16x8 o;
    #pragma unroll
    for (int e=0;e<8;e++) o[e] = f2bf(w1 * bf2f(o1[e]) + w2 * bf2f(o2[e]));
    *(s16x8*)(av + ((size_t)(b*SEQ + qrow))*DMODEL + h*64 + d8) = o;
}

// ---------------------------------------------------------------- launch
extern "C" void kernel_launch(void* const* d_in, const int* in_sizes, int n_in,
                              void* d_out, int out_size, void* d_ws, size_t ws_size,
                              hipStream_t stream)
{
    const float* query = (const float*)d_in[0];
    const float* key   = (const float*)d_in[1];
    const float* value = (const float*)d_in[2];
    const float* Wq    = (const float*)d_in[3];
    const float* Wk    = (const float*)d_in[4];
    const float* Wv    = (const float*)d_in[5];
    const float* Wo    = (const float*)d_in[6];
    const float* gW    = (const float*)d_in[7];
    const float* gB    = (const float*)d_in[8];
    const float* qg    = (const float*)d_in[9];
    const float* qb    = (const float*)d_in[10];
    const float* kg    = (const float*)d_in[11];
    const float* kb    = (const float*)d_in[12];
    const float* vg    = (const float*)d_in[13];
    const float* vb    = (const float*)d_in[14];
    const int* qmask   = (const int*)d_in[15];
    const int* kmask   = (const int*)d_in[16];
    float* out = (float*)d_out;
    char* ws = (char*)d_ws;

    if (ws_size < WS_NEEDED) return;

    short* qn  = (short*)(ws + OFF_QN);
    short* kn  = (short*)(ws + OFF_KN);
    short* vn  = (short*)(ws + OFF_VN);
    short* qh  = (short*)(ws + OFF_QH);
    short* khp = (short*)(ws + OFF_KH);
    short* vhp = (short*)(ws + OFF_VH);
    short* vhT = (short*)(ws + OFF_VHT);
    short* av  = (short*)(ws + OFF_AV);
    short* WT  = (short*)(ws + OFF_WQT);
    short* WoT = WT + 3*262144;
    short* gWT = WT + 1048576;
    short* On  = (short*)(ws + OFF_ON);
    float* mlp = (float*)(ws + OFF_ML);
    float* kbp = (float*)(ws + OFF_KB);
    float* ap  = (float*)(ws + OFF_AP);

    // 1. layernorm + cast, all three tensors (K/V padded to 2080 rows/batch)
    ln_all<<<3104, 256, 0, stream>>>(query, key, value, qg, qb, kg, kb, vg, vb, qn, kn, vn);

    // 2. all weights -> bf16 transposed + kbias
    wt_all<<<1553, 256, 0, stream>>>(Wq, Wk, Wv, Wo, gW, WT, kmask, kbp);

    // 3. fused QKV projection (coalesced row writes)
    qkv_gemm<<<1552, 256, 0, stream>>>(qn, WT, qh, khp, vhp);

    // 4. V transpose for PV MFMA B-operand
    transpose_v<<<528, 256, 0, stream>>>(vhp, vhT);

    // 5. flash attention, split-KV 2-way, XCD-local heads
    flash_kernel<<<1024, 256, 0, stream>>>(qh, khp, vhT, kbp, On, mlp);
    merge_kernel<<<1024, 256, 0, stream>>>(On, mlp, qmask, av);

    // 6. output projection (f32 out)
    gemm64f<<<512, 256, 0, stream>>>(av, WoT, ap, 4096, 512, 512);

    // 7. gate GEMM fused: concat-stage + sigmoid + residual
    gate_gemm<<<512, 256, 0, stream>>>(query, ap, gWT, gB, out);

    (void)in_sizes; (void)n_in; (void)out_size;
}

// Round 7
// 283.756 us; speedup vs baseline: 1.1568x; 1.1568x over previous
//
#include <hip/hip_runtime.h>

typedef float f32x4 __attribute__((ext_vector_type(4)));
typedef short s16x8 __attribute__((ext_vector_type(8)));

#define DEV __device__ __forceinline__

DEV short f2bf(float f) {
    union { float f; unsigned u; } v; v.f = f;
    unsigned r = v.u + 0x7fffu + ((v.u >> 16) & 1u);
    return (short)(r >> 16);
}
DEV float bf2f(short s) {
    union { unsigned u; float f; } v; v.u = ((unsigned)(unsigned short)s) << 16;
    return v.f;
}

// B=2, Q=K=2048, D=512, H=8, hd=64. KV padded: 2048 real + 1 zero-attn + 31 pad = 2080.
// kn/vn additionally padded to 4224 rows (multiple of 128) with zeros for 128-row GEMM tiles.
#define SEQ    2048
#define DMODEL 512
#define KPAD   2080
#define NROWS  32768   /* B*H*SEQ flash output rows */

// ws layout (bytes). qn|kn|vn contiguous (A of the single QKV GEMM), weights contiguous.
#define OFF_QN   0ull            /* 4096 rows  = 4,194,304 */
#define OFF_KN   4194304ull      /* 4224 rows  = 4,325,376 */
#define OFF_VN   8519680ull      /* 4224 rows  -> ends 12,845,056 */
#define OFF_QH   12845056ull     /* 4,194,304 */
#define OFF_KH   17039360ull     /* 4160 rows = 4,259,840 -> ends 21,299,200 */
#define OFF_VH   21364736ull     /* vhp 4,259,840 -> ends 25,624,576 */
#define OFF_VHT  25690112ull     /* 4,259,840 -> ends 29,949,952 */
#define OFF_AV   29949952ull     /* 4,194,304 */
#define OFF_WQT  34144256ull     /* WqT|WkT|WvT|WoT|gWT = 4*524,288 + 1,048,576 */
#define WS_NEEDED 37289984ull
// aliased (lifetimes disjoint):
#define OFF_ON   0ull            /* flash partials bf16 [3][32768][64] = 12,582,912 over qn|kn|vn (dead post-qkv) */
#define OFF_ML   21364736ull     /* (m,l) f32 [3][32768][2] = 786,432 over vhp (dead post-transpose; read by merge before ap write) */
#define OFF_KB   29949952ull     /* key bias f32 2*2080*4 over av region (flash reads it before merge writes av) */
#define OFF_AP   17039360ull     /* attn_proj f32 8,388,608 over kh+vhp (dead post-flash/merge) */

// ---------------------------------------------------------------- fused LayerNorm+cast (q,k,v)
__global__ __launch_bounds__(256) void ln_all(
    const float* __restrict__ q, const float* __restrict__ k, const float* __restrict__ v,
    const float* __restrict__ qg, const float* __restrict__ qb,
    const float* __restrict__ kg, const float* __restrict__ kb2,
    const float* __restrict__ vg, const float* __restrict__ vb,
    short* __restrict__ qn, short* __restrict__ kn, short* __restrict__ vn)
{
    int bid = blockIdx.x;
    const float *in, *gamma, *beta; short* out; int Sreal, Spad;
    if (bid < 1024)      { in=q; gamma=qg; beta=qb;  out=qn; Sreal=SEQ; Spad=SEQ;  }
    else if (bid < 2080) { bid-=1024; in=k; gamma=kg; beta=kb2; out=kn; Sreal=SEQ; Spad=KPAD; }
    else                 { bid-=2080; in=v; gamma=vg; beta=vb;  out=vn; Sreal=SEQ; Spad=KPAD; }

    int w = threadIdx.x >> 6, l = threadIdx.x & 63;
    int r = bid * 4 + w;
    short* op = out + (size_t)r * DMODEL + l * 8;
    s16x8 o = {0,0,0,0,0,0,0,0};
    if (r >= 2 * Spad) { *(s16x8*)op = o; return; }   // zero pad rows (incl. 4160..4223)
    int b = r / Spad, j = r - b * Spad;
    if (j >= Sreal) {
        if (j == Sreal) {
            f32x4 b0 = *(const f32x4*)(beta + l*8);
            f32x4 b1 = *(const f32x4*)(beta + l*8 + 4);
            #pragma unroll
            for (int t=0;t<4;t++){ o[t]=f2bf(b0[t]); o[t+4]=f2bf(b1[t]); }
        }
        *(s16x8*)op = o; return;
    }
    const float* ip = in + ((size_t)b * Sreal + j) * DMODEL + l * 8;
    f32x4 x0 = *(const f32x4*)ip;
    f32x4 x1 = *(const f32x4*)(ip + 4);
    float s = x0[0]+x0[1]+x0[2]+x0[3]+x1[0]+x1[1]+x1[2]+x1[3];
    #pragma unroll
    for (int off=1; off<64; off<<=1) s += __shfl_xor(s, off);
    float mean = s * (1.0f/512.0f);
    float vs = 0.f;
    #pragma unroll
    for (int t=0;t<4;t++){ float d0=x0[t]-mean, d1=x1[t]-mean; vs += d0*d0 + d1*d1; }
    #pragma unroll
    for (int off=1; off<64; off<<=1) vs += __shfl_xor(vs, off);
    float rstd = rsqrtf(vs * (1.0f/512.0f) + 1e-5f);
    f32x4 g0 = *(const f32x4*)(gamma + l*8), g1 = *(const f32x4*)(gamma + l*8 + 4);
    f32x4 b0 = *(const f32x4*)(beta + l*8),  b1 = *(const f32x4*)(beta + l*8 + 4);
    #pragma unroll
    for (int t=0;t<4;t++){
        o[t]   = f2bf((x0[t]-mean)*rstd*g0[t] + b0[t]);
        o[t+4] = f2bf((x1[t]-mean)*rstd*g1[t] + b1[t]);
    }
    *(s16x8*)op = o;
}

// ---------------------------------------------------------------- all weights transpose+cast + kbias
__global__ __launch_bounds__(256) void wt_all(
    const float* __restrict__ Wq, const float* __restrict__ Wk,
    const float* __restrict__ Wv, const float* __restrict__ Wo,
    const float* __restrict__ gW, short* __restrict__ WT,
    const int* __restrict__ km, float* __restrict__ kbias)
{
    int bid = blockIdx.x;
    if (bid >= 1536) {
        int i = (bid - 1536) * 256 + threadIdx.x;
        if (i >= 2 * KPAD) return;
        int b = i / KPAD, j = i - b * KPAD;
        float v;
        if (j < SEQ)       v = km[b*SEQ + j] ? 0.0f : -1e30f;
        else if (j == SEQ) v = 0.0f;     // zero-attn slot (mask bit 1)
        else               v = -1e30f;   // pad rows
        kbias[i] = v;
        return;
    }
    const float* in; short* out; int K;
    if (bid < 1024) {
        int wsel = bid >> 8;
        in = (wsel==0) ? Wq : (wsel==1) ? Wk : (wsel==2) ? Wv : Wo;
        out = WT + (size_t)wsel * 262144;
        K = 512; bid &= 255;
    } else {
        in = gW; out = WT + 1048576; K = 1024; bid -= 1024;
    }
    __shared__ float t[32][33];
    int bx = bid & 15, by = bid >> 4;   // N=512 always -> 16 col tiles
    int n0 = bx * 32, k0 = by * 32;
    int tx = threadIdx.x & 31, ty = threadIdx.x >> 5;
    #pragma unroll
    for (int i=0;i<4;i++)
        t[ty + i*8][tx] = in[(size_t)(k0 + ty + i*8) * 512 + n0 + tx];
    __syncthreads();
    #pragma unroll
    for (int i=0;i<4;i++)
        out[(size_t)(n0 + ty + i*8) * K + k0 + tx] = f2bf(t[tx][ty + i*8]);
}

// ---------------------------------------------------------------- unified 128x64-tile GEMM
// Tile: M=128 (4 waves x 32 rows), N=64, BK=64. acc 2x4. 16 MFMA / K-step / wave.
// MODE 0: qkv — A bf16 (12544,512), B = WT seg by row range, split bf16 writes.
// MODE 1: Wo  — A bf16, f32 C out.
// MODE 2: gate — A = concat(query, ap) f32 staged->bf16, gate+residual epilogue.
template<int MODE, int KK>
__global__ __launch_bounds__(256) void gemm_u(
    const short* __restrict__ A, const float* __restrict__ F1, const float* __restrict__ F2,
    const short* __restrict__ WT,
    short* __restrict__ O0, short* __restrict__ O1, short* __restrict__ O2,
    float* __restrict__ FO, const float* __restrict__ bias)
{
    __shared__ short As[128*64];
    __shared__ short Bs[64*64];
    int tid = threadIdx.x;
    int w = tid >> 6, l = tid & 63;
    int lr = l & 15, lg = l >> 4;
    int tn = blockIdx.x & 7, tm = blockIdx.x >> 3;
    int srow = tid >> 3, sslot = tid & 7;

    const short* Bseg = WT;
    if (MODE == 0) {
        int seg = (tm < 32) ? 0 : (tm < 65) ? 1 : 2;   // 4096 | 8320 row boundaries
        Bseg = WT + (size_t)seg * 262144;
    }

    f32x4 acc[2][4];
    #pragma unroll
    for (int m=0;m<2;m++)
        #pragma unroll
        for (int n=0;n<4;n++) acc[m][n] = (f32x4){0.f,0.f,0.f,0.f};

    for (int k0 = 0; k0 < KK; k0 += 64) {
        // B staging (64 rows)
        #pragma unroll
        for (int i=0;i<2;i++){
            int row = i*32 + srow;
            int gslot = sslot ^ (row & 7);
            const short* gb = Bseg + (size_t)(tn*64 + row) * KK + k0 + gslot*8;
            short* lb = Bs + (i*256 + w*64) * 8;
            __builtin_amdgcn_global_load_lds((const __attribute__((address_space(1))) void*)gb,
                                             (__attribute__((address_space(3))) void*)lb, 16, 0, 0);
        }
        // A staging (128 rows)
        if (MODE != 2) {
            #pragma unroll
            for (int i=0;i<4;i++){
                int row = i*32 + srow;
                int gslot = sslot ^ (row & 7);
                const short* ga = A + (size_t)(tm*128 + row) * KK + k0 + gslot*8;
                short* la = As + (i*256 + w*64) * 8;
                __builtin_amdgcn_global_load_lds((const __attribute__((address_space(1))) void*)ga,
                                                 (__attribute__((address_space(3))) void*)la, 16, 0, 0);
            }
        } else {
            const float* src = (k0 < 512) ? F1 : F2;
            int csub = (k0 < 512) ? k0 : k0 - 512;
            #pragma unroll
            for (int i=0;i<4;i++){
                int row = i*32 + srow;
                const float* gp = src + (size_t)(tm*128 + row) * 512 + csub + sslot*8;
                f32x4 a0 = *(const f32x4*)gp;
                f32x4 a1 = *(const f32x4*)(gp + 4);
                s16x8 o;
                #pragma unroll
                for (int t=0;t<4;t++){ o[t] = f2bf(a0[t]); o[t+4] = f2bf(a1[t]); }
                *(s16x8*)(As + row*64 + (sslot ^ (row & 7))*8) = o;
            }
        }
        __syncthreads();
        #pragma unroll
        for (int s=0;s<2;s++){
            s16x8 af[2], bfr[4];
            #pragma unroll
            for (int m=0;m<2;m++){
                int row = w*32 + m*16 + lr;
                int slot = (s*4 + lg) ^ (row & 7);
                af[m] = *(const s16x8*)(As + row*64 + slot*8);
            }
            #pragma unroll
            for (int n=0;n<4;n++){
                int row = n*16 + lr;
                int slot = (s*4 + lg) ^ (row & 7);
                bfr[n] = *(const s16x8*)(Bs + row*64 + slot*8);
            }
            #pragma unroll
            for (int m=0;m<2;m++)
                #pragma unroll
                for (int n=0;n<4;n++)
                    acc[m][n] = __builtin_amdgcn_mfma_f32_16x16x32_bf16(af[m], bfr[n], acc[m][n], 0, 0, 0);
        }
        __syncthreads();
    }

    #pragma unroll
    for (int n=0;n<4;n++){
        int col = tn*64 + n*16 + lr;
        float badd = (MODE == 2) ? bias[col] : 0.0f;
        #pragma unroll
        for (int m=0;m<2;m++){
            #pragma unroll
            for (int j=0;j<4;j++){
                int row = tm*128 + w*32 + m*16 + lg*4 + j;
                float v = acc[m][n][j];
                if (MODE == 0) {
                    short bv = f2bf(v);
                    if (row < 4096) {
                        O0[(size_t)row*512 + col] = bv;
                    } else if (row < 8320) {
                        int r2 = row - 4096;
                        if (r2 < 4160) O1[(size_t)r2*512 + col] = bv;
                    } else {
                        int r2 = row - 8320;
                        if (r2 < 4160) O2[(size_t)r2*512 + col] = bv;
                    }
                } else if (MODE == 1) {
                    FO[(size_t)row*512 + col] = v;
                } else {
                    size_t idx = (size_t)row*512 + col;
                    float g = 1.0f / (1.0f + __expf(-(v + badd)));
                    float q = F1[idx], a = F2[idx];
                    FO[idx] = q + g*q + (1.0f - g)*a;
                }
            }
        }
    }
}

// ---------------------------------------------------------------- vhp -> vhT[b][h][64][KPAD]
__global__ __launch_bounds__(256) void transpose_v(
    const short* __restrict__ vh, short* __restrict__ vhT)
{
    __shared__ short t[64][72];
    int tid = threadIdx.x, bid = blockIdx.x;
    int kt = bid % 33; int hh = (bid / 33) & 7; int b = bid / (33*8);
    int k0 = kt * 64;
    int rr = tid >> 3, c8 = (tid & 7) * 8;
    #pragma unroll
    for (int p=0;p<2;p++){
        int kr = p*32 + rr;
        int gk = k0 + kr;
        s16x8 v = {0,0,0,0,0,0,0,0};
        if (gk < KPAD) v = *(const s16x8*)(vh + (size_t)(b*KPAD + gk)*DMODEL + hh*64 + c8);
        *(s16x8*)&t[kr][c8] = v;
    }
    __syncthreads();
    #pragma unroll
    for (int p=0;p<2;p++){
        int dr = p*32 + rr;
        if (k0 + c8 < KPAD){
            s16x8 o;
            #pragma unroll
            for (int j2=0;j2<8;j2++) o[j2] = t[c8+j2][dr];
            *(s16x8*)(vhT + ((size_t)(b*8 + hh)*64 + dr)*KPAD + k0 + c8) = o;
        }
    }
}

// ---------------------------------------------------------------- flash attention, split-KV 3-way
// bid = ((qblk*3 + split)*2 + b)*8 + h  ->  bid%8 == h: each XCD owns one head
// (K+V+Q slice ~2.6 MB, L2-resident). Round-4 spill-free body: inline K and V loads.
__global__ __launch_bounds__(256, 6) void flash_kernel(
    const short* __restrict__ qh, const short* __restrict__ kh,
    const short* __restrict__ vhT, const float* __restrict__ kbias,
    short* __restrict__ On, float* __restrict__ ml)
{
    __shared__ short plds[4][16*72];
    int tid = threadIdx.x;
    int w = tid >> 6, l = tid & 63;
    int bid = blockIdx.x;
    int h = bid & 7;
    int b = (bid >> 3) & 1;
    int t = bid >> 4;            // 0..95
    int qblk = t / 3;
    int split = t - qblk * 3;
    int q0 = (qblk * 4 + w) << 4;
    int cl = l & 15, rg = l >> 4;

    const short* qp = qh + ((size_t)(b*SEQ + q0 + cl))*DMODEL + h*64 + rg*8;
    s16x8 qf0 = *(const s16x8*)qp;
    s16x8 qf1 = *(const s16x8*)(qp + 32);

    f32x4 O[4];
    float mrow[4], lsum[4];
    #pragma unroll
    for (int n=0;n<4;n++) O[n] = (f32x4){0.f,0.f,0.f,0.f};
    #pragma unroll
    for (int j=0;j<4;j++){ mrow[j] = -1e30f; lsum[j] = 0.f; }

    const short* khb = kh + (size_t)b*KPAD*DMODEL + h*64;
    const short* vtb = vhT + (size_t)(b*8 + h)*64*KPAD;
    const float* kbb = kbias + b*KPAD;
    short* pl = plds[w];

    int kc0 = split * 11;
    int kcN = kc0 + ((split == 2) ? 10 : 11);
    for (int kc = kc0; kc < kcN; ++kc) {
        int k0 = kc * 64;
        float sv[4][4];
        #pragma unroll
        for (int nh=0; nh<4; ++nh) {
            const short* kp = khb + (size_t)(k0 + nh*16 + cl)*DMODEL + rg*8;
            s16x8 ka = *(const s16x8*)kp;
            s16x8 kb2 = *(const s16x8*)(kp + 32);
            f32x4 z = (f32x4){0.f,0.f,0.f,0.f};
            z = __builtin_amdgcn_mfma_f32_16x16x32_bf16(qf0, ka,  z, 0, 0, 0);
            z = __builtin_amdgcn_mfma_f32_16x16x32_bf16(qf1, kb2, z, 0, 0, 0);
            float bias = kbb[k0 + nh*16 + cl];
            #pragma unroll
            for (int j=0;j<4;j++) sv[nh][j] = fmaf(z[j], 0.125f, bias);
        }
        float ml4[4];
        #pragma unroll
        for (int j=0;j<4;j++)
            ml4[j] = fmaxf(fmaxf(sv[0][j], sv[1][j]), fmaxf(sv[2][j], sv[3][j]));
        #pragma unroll
        for (int off=1; off<16; off<<=1){
            #pragma unroll
            for (int j=0;j<4;j++) ml4[j] = fmaxf(ml4[j], __shfl_xor(ml4[j], off));
        }
        bool need = (ml4[0] > mrow[0]+8.f) || (ml4[1] > mrow[1]+8.f) ||
                    (ml4[2] > mrow[2]+8.f) || (ml4[3] > mrow[3]+8.f);
        if (__any(need)) {
            #pragma unroll
            for (int j=0;j<4;j++){
                float mn = fmaxf(mrow[j], ml4[j]);
                float sc = __expf(mrow[j] - mn);
                mrow[j] = mn; lsum[j] *= sc;
                #pragma unroll
                for (int n=0;n<4;n++) O[n][j] *= sc;
            }
        }
        float ps[4] = {0.f,0.f,0.f,0.f};
        #pragma unroll
        for (int nh=0; nh<4; ++nh){
            #pragma unroll
            for (int j=0;j<4;j++){
                float p = __expf(sv[nh][j] - mrow[j]);
                ps[j] += p;
                pl[(rg*4 + j)*72 + nh*16 + cl] = f2bf(p);
            }
        }
        #pragma unroll
        for (int off=1; off<16; off<<=1){
            #pragma unroll
            for (int j=0;j<4;j++) ps[j] += __shfl_xor(ps[j], off);
        }
        #pragma unroll
        for (int j=0;j<4;j++) lsum[j] += ps[j];

        s16x8 pa0 = *(const s16x8*)(pl + cl*72 + rg*8);
        s16x8 pa1 = *(const s16x8*)(pl + cl*72 + 32 + rg*8);
        __builtin_amdgcn_s_setprio(1);
        #pragma unroll
        for (int n=0;n<4;n++){
            s16x8 vf0 = *(const s16x8*)(vtb + (size_t)(n*16 + cl)*KPAD + k0 + rg*8);
            s16x8 vf1 = *(const s16x8*)(vtb + (size_t)(n*16 + cl)*KPAD + k0 + 32 + rg*8);
            O[n] = __builtin_amdgcn_mfma_f32_16x16x32_bf16(pa0, vf0, O[n], 0, 0, 0);
            O[n] = __builtin_amdgcn_mfma_f32_16x16x32_bf16(pa1, vf1, O[n], 0, 0, 0);
        }
        __builtin_amdgcn_s_setprio(0);
    }

    if (split == 2) {  // tail: keys 2048..2079
        int k0 = 2048;
        float sv[2][4];
        #pragma unroll
        for (int nh=0; nh<2; ++nh) {
            const short* kp = khb + (size_t)(k0 + nh*16 + cl)*DMODEL + rg*8;
            s16x8 ka = *(const s16x8*)kp;
            s16x8 kb2 = *(const s16x8*)(kp + 32);
            f32x4 z = (f32x4){0.f,0.f,0.f,0.f};
            z = __builtin_amdgcn_mfma_f32_16x16x32_bf16(qf0, ka,  z, 0, 0, 0);
            z = __builtin_amdgcn_mfma_f32_16x16x32_bf16(qf1, kb2, z, 0, 0, 0);
            float bias = kbb[k0 + nh*16 + cl];
            #pragma unroll
            for (int j=0;j<4;j++) sv[nh][j] = fmaf(z[j], 0.125f, bias);
        }
        float ml4[4];
        #pragma unroll
        for (int j=0;j<4;j++) ml4[j] = fmaxf(sv[0][j], sv[1][j]);
        #pragma unroll
        for (int off=1; off<16; off<<=1){
            #pragma unroll
            for (int j=0;j<4;j++) ml4[j] = fmaxf(ml4[j], __shfl_xor(ml4[j], off));
        }
        bool need = (ml4[0] > mrow[0]+8.f) || (ml4[1] > mrow[1]+8.f) ||
                    (ml4[2] > mrow[2]+8.f) || (ml4[3] > mrow[3]+8.f);
        if (__any(need)) {
            #pragma unroll
            for (int j=0;j<4;j++){
                float mn = fmaxf(mrow[j], ml4[j]);
                float sc = __expf(mrow[j] - mn);
                mrow[j] = mn; lsum[j] *= sc;
                #pragma unroll
                for (int n=0;n<4;n++) O[n][j] *= sc;
            }
        }
        float ps[4] = {0.f,0.f,0.f,0.f};
        #pragma unroll
        for (int nh=0; nh<2; ++nh){
            #pragma unroll
            for (int j=0;j<4;j++){
                float p = __expf(sv[nh][j] - mrow[j]);
                ps[j] += p;
                pl[(rg*4 + j)*72 + nh*16 + cl] = f2bf(p);
            }
        }
        #pragma unroll
        for (int off=1; off<16; off<<=1){
            #pragma unroll
            for (int j=0;j<4;j++) ps[j] += __shfl_xor(ps[j], off);
        }
        #pragma unroll
        for (int j=0;j<4;j++) lsum[j] += ps[j];

        s16x8 pa0 = *(const s16x8*)(pl + cl*72 + rg*8);
        __builtin_amdgcn_s_setprio(1);
        #pragma unroll
        for (int n=0;n<4;n++){
            s16x8 vf0 = *(const s16x8*)(vtb + (size_t)(n*16 + cl)*KPAD + k0 + rg*8);
            O[n] = __builtin_amdgcn_mfma_f32_16x16x32_bf16(pa0, vf0, O[n], 0, 0, 0);
        }
        __builtin_amdgcn_s_setprio(0);
    }

    // store normalized partial + (m, l)
    int rbase = ((b*8 + h) << 11) + q0;
    #pragma unroll
    for (int j=0;j<4;j++){
        int r = rbase + rg*4 + j;
        float invl = 1.0f / lsum[j];
        #pragma unroll
        for (int n=0;n<4;n++)
            On[((size_t)split*NROWS + r)*64 + n*16 + cl] = f2bf(O[n][j] * invl);
        if (cl == 0){
            ml[((size_t)split*NROWS + r)*2    ] = mrow[j];
            ml[((size_t)split*NROWS + r)*2 + 1] = lsum[j];
        }
    }
}

// ---------------------------------------------------------------- merge 3 split-KV partials -> av bf16
__global__ __launch_bounds__(256) void merge_kernel(
    const short* __restrict__ On, const float* __restrict__ ml,
    const int* __restrict__ qmask, short* __restrict__ av)
{
    int tid = threadIdx.x;
    int r = blockIdx.x * 32 + (tid >> 3);
    int d8 = (tid & 7) * 8;
    float m0 = ml[(size_t)r*2],              l0 = ml[(size_t)r*2 + 1];
    float m1 = ml[((size_t)NROWS + r)*2],    l1 = ml[((size_t)NROWS + r)*2 + 1];
    float m2 = ml[((size_t)2*NROWS + r)*2],  l2 = ml[((size_t)2*NROWS + r)*2 + 1];
    float m = fmaxf(m0, fmaxf(m1, m2));
    float w0 = l0 * __expf(m0 - m), w1 = l1 * __expf(m1 - m), w2 = l2 * __expf(m2 - m);
    int qrow = r & 2047, bh = r >> 11, h = bh & 7, b = bh >> 3;
    int qm = qmask[b*SEQ + qrow];
    float inv = qm ? 1.0f / (w0 + w1 + w2) : 0.0f;
    w0 *= inv; w1 *= inv; w2 *= inv;
    s16x8 o0 = *(const s16x8*)(On + (size_t)r*64 + d8);
    s16x8 o1 = *(const s16x8*)(On + ((size_t)NROWS + r)*64 + d8);
    s16x8 o2 = *(const s16x8*)(On + ((size_t)2*NROWS + r)*64 + d8);
    s16x8 o;
    #pragma unroll
    for (int e=0;e<8;e++) o[e] = f2bf(w0*bf2f(o0[e]) + w1*bf2f(o1[e]) + w2*bf2f(o2[e]));
    *(s16x8*)(av + ((size_t)(b*SEQ + qrow))*DMODEL + h*64 + d8) = o;
}

// ---------------------------------------------------------------- launch
extern "C" void kernel_launch(void* const* d_in, const int* in_sizes, int n_in,
                              void* d_out, int out_size, void* d_ws, size_t ws_size,
                              hipStream_t stream)
{
    const float* query = (const float*)d_in[0];
    const float* key   = (const float*)d_in[1];
    const float* value = (const float*)d_in[2];
    const float* Wq    = (const float*)d_in[3];
    const float* Wk    = (const float*)d_in[4];
    const float* Wv    = (const float*)d_in[5];
    const float* Wo    = (const float*)d_in[6];
    const float* gW    = (const float*)d_in[7];
    const float* gB    = (const float*)d_in[8];
    const float* qg    = (const float*)d_in[9];
    const float* qb    = (const float*)d_in[10];
    const float* kg    = (const float*)d_in[11];
    const float* kb    = (const float*)d_in[12];
    const float* vg    = (const float*)d_in[13];
    const float* vb    = (const float*)d_in[14];
    const int* qmask   = (const int*)d_in[15];
    const int* kmask   = (const int*)d_in[16];
    float* out = (float*)d_out;
    char* ws = (char*)d_ws;

    if (ws_size < WS_NEEDED) return;

    short* qn  = (short*)(ws + OFF_QN);
    short* kn  = (short*)(ws + OFF_KN);
    short* vn  = (short*)(ws + OFF_VN);
    short* qh  = (short*)(ws + OFF_QH);
    short* khp = (short*)(ws + OFF_KH);
    short* vhp = (short*)(ws + OFF_VH);
    short* vhT = (short*)(ws + OFF_VHT);
    short* av  = (short*)(ws + OFF_AV);
    short* WT  = (short*)(ws + OFF_WQT);
    short* WoT = WT + 3*262144;
    short* gWT = WT + 1048576;
    short* On  = (short*)(ws + OFF_ON);
    float* mlp = (float*)(ws + OFF_ML);
    float* kbp = (float*)(ws + OFF_KB);
    float* ap  = (float*)(ws + OFF_AP);

    // 1. layernorm + cast (kn/vn zero-padded to 4224 rows)
    ln_all<<<3136, 256, 0, stream>>>(query, key, value, qg, qb, kg, kb, vg, vb, qn, kn, vn);

    // 2. all weights -> bf16 transposed + kbias
    wt_all<<<1553, 256, 0, stream>>>(Wq, Wk, Wv, Wo, gW, WT, kmask, kbp);

    // 3. fused QKV projection, 128x64 tiles (98 Mtiles x 8 Ntiles)
    gemm_u<0,512><<<784, 256, 0, stream>>>(qn, nullptr, nullptr, WT, qh, khp, vhp, nullptr, nullptr);

    // 4. V transpose for PV MFMA B-operand
    transpose_v<<<528, 256, 0, stream>>>(vhp, vhT);

    // 5. flash attention, split-KV 3-way, XCD-local heads
    flash_kernel<<<1536, 256, 0, stream>>>(qh, khp, vhT, kbp, On, mlp);
    merge_kernel<<<1024, 256, 0, stream>>>(On, mlp, qmask, av);

    // 6. output projection (f32 out)
    gemm_u<1,512><<<256, 256, 0, stream>>>(av, nullptr, nullptr, WoT, nullptr, nullptr, nullptr, ap, nullptr);

    // 7. gate GEMM fused: concat-stage + sigmoid + residual
    gemm_u<2,1024><<<256, 256, 0, stream>>>(nullptr, query, ap, gWT, nullptr, nullptr, nullptr, out, gB);

    (void)in_sizes; (void)n_in; (void)out_size;
}

// Round 8
// 240.198 us; speedup vs baseline: 1.3666x; 1.1813x over previous
//
#include <hip/hip_runtime.h>

typedef float f32x4 __attribute__((ext_vector_type(4)));
typedef short s16x8 __attribute__((ext_vector_type(8)));

#define DEV __device__ __forceinline__

DEV short f2bf(float f) {
    union { float f; unsigned u; } v; v.f = f;
    unsigned r = v.u + 0x7fffu + ((v.u >> 16) & 1u);
    return (short)(r >> 16);
}
DEV float bf2f(short s) {
    union { unsigned u; float f; } v; v.u = ((unsigned)(unsigned short)s) << 16;
    return v.f;
}

// B=2, Q=K=2048, D=512, H=8, hd=64. KV padded: 2048 real + 1 zero-attn + 31 pad = 2080.
// kn/vn additionally padded to 4224 rows (multiple of 128) with zeros for 128-row GEMM tiles.
#define SEQ    2048
#define DMODEL 512
#define KPAD   2080
#define NROWS  32768   /* B*H*SEQ flash output rows */

// ws layout (bytes). qn|kn|vn contiguous (A of the single QKV GEMM), weights contiguous.
#define OFF_QN   0ull            /* 4096 rows  = 4,194,304 */
#define OFF_KN   4194304ull      /* 4224 rows  = 4,325,376 */
#define OFF_VN   8519680ull      /* 4224 rows  -> ends 12,845,056 */
#define OFF_QH   12845056ull     /* 4,194,304 */
#define OFF_KH   17039360ull     /* 4160 rows = 4,259,840 -> ends 21,299,200 */
#define OFF_VH   21364736ull     /* vhp 4,259,840 -> ends 25,624,576 */
#define OFF_VHT  25690112ull     /* 4,259,840 -> ends 29,949,952 */
#define OFF_AV   29949952ull     /* 4,194,304 */
#define OFF_WQT  34144256ull     /* WqT|WkT|WvT|WoT|gWT = 4*524,288 + 1,048,576 */
#define WS_NEEDED 37289984ull
// aliased (lifetimes disjoint):
#define OFF_ON   0ull            /* flash partials bf16 [3][32768][64] = 12,582,912 over qn|kn|vn (dead post-qkv) */
#define OFF_ML   21364736ull     /* (m,l) f32 [3][32768][2] = 786,432 over vhp (dead post-transpose; read by merge before ap write) */
#define OFF_KB   29949952ull     /* key bias f32 2*2080*4 over av region (flash reads it before merge writes av) */
#define OFF_AP   17039360ull     /* attn_proj f32 8,388,608 over kh+vhp (dead post-flash/merge) */

// ---------------------------------------------------------------- fused LayerNorm+cast (q,k,v)
__global__ __launch_bounds__(256) void ln_all(
    const float* __restrict__ q, const float* __restrict__ k, const float* __restrict__ v,
    const float* __restrict__ qg, const float* __restrict__ qb,
    const float* __restrict__ kg, const float* __restrict__ kb2,
    const float* __restrict__ vg, const float* __restrict__ vb,
    short* __restrict__ qn, short* __restrict__ kn, short* __restrict__ vn)
{
    int bid = blockIdx.x;
    const float *in, *gamma, *beta; short* out; int Sreal, Spad;
    if (bid < 1024)      { in=q; gamma=qg; beta=qb;  out=qn; Sreal=SEQ; Spad=SEQ;  }
    else if (bid < 2080) { bid-=1024; in=k; gamma=kg; beta=kb2; out=kn; Sreal=SEQ; Spad=KPAD; }
    else                 { bid-=2080; in=v; gamma=vg; beta=vb;  out=vn; Sreal=SEQ; Spad=KPAD; }

    int w = threadIdx.x >> 6, l = threadIdx.x & 63;
    int r = bid * 4 + w;
    short* op = out + (size_t)r * DMODEL + l * 8;
    s16x8 o = {0,0,0,0,0,0,0,0};
    if (r >= 2 * Spad) { *(s16x8*)op = o; return; }   // zero pad rows (incl. 4160..4223)
    int b = r / Spad, j = r - b * Spad;
    if (j >= Sreal) {
        if (j == Sreal) {
            f32x4 b0 = *(const f32x4*)(beta + l*8);
            f32x4 b1 = *(const f32x4*)(beta + l*8 + 4);
            #pragma unroll
            for (int t=0;t<4;t++){ o[t]=f2bf(b0[t]); o[t+4]=f2bf(b1[t]); }
        }
        *(s16x8*)op = o; return;
    }
    const float* ip = in + ((size_t)b * Sreal + j) * DMODEL + l * 8;
    f32x4 x0 = *(const f32x4*)ip;
    f32x4 x1 = *(const f32x4*)(ip + 4);
    float s = x0[0]+x0[1]+x0[2]+x0[3]+x1[0]+x1[1]+x1[2]+x1[3];
    #pragma unroll
    for (int off=1; off<64; off<<=1) s += __shfl_xor(s, off);
    float mean = s * (1.0f/512.0f);
    float vs = 0.f;
    #pragma unroll
    for (int t=0;t<4;t++){ float d0=x0[t]-mean, d1=x1[t]-mean; vs += d0*d0 + d1*d1; }
    #pragma unroll
    for (int off=1; off<64; off<<=1) vs += __shfl_xor(vs, off);
    float rstd = rsqrtf(vs * (1.0f/512.0f) + 1e-5f);
    f32x4 g0 = *(const f32x4*)(gamma + l*8), g1 = *(const f32x4*)(gamma + l*8 + 4);
    f32x4 b0 = *(const f32x4*)(beta + l*8),  b1 = *(const f32x4*)(beta + l*8 + 4);
    #pragma unroll
    for (int t=0;t<4;t++){
        o[t]   = f2bf((x0[t]-mean)*rstd*g0[t] + b0[t]);
        o[t+4] = f2bf((x1[t]-mean)*rstd*g1[t] + b1[t]);
    }
    *(s16x8*)op = o;
}

// ---------------------------------------------------------------- all weights transpose+cast + kbias
__global__ __launch_bounds__(256) void wt_all(
    const float* __restrict__ Wq, const float* __restrict__ Wk,
    const float* __restrict__ Wv, const float* __restrict__ Wo,
    const float* __restrict__ gW, short* __restrict__ WT,
    const int* __restrict__ km, float* __restrict__ kbias)
{
    int bid = blockIdx.x;
    if (bid >= 1536) {
        int i = (bid - 1536) * 256 + threadIdx.x;
        if (i >= 2 * KPAD) return;
        int b = i / KPAD, j = i - b * KPAD;
        float v;
        if (j < SEQ)       v = km[b*SEQ + j] ? 0.0f : -1e30f;
        else if (j == SEQ) v = 0.0f;     // zero-attn slot (mask bit 1)
        else               v = -1e30f;   // pad rows
        kbias[i] = v;
        return;
    }
    const float* in; short* out; int K;
    if (bid < 1024) {
        int wsel = bid >> 8;
        in = (wsel==0) ? Wq : (wsel==1) ? Wk : (wsel==2) ? Wv : Wo;
        out = WT + (size_t)wsel * 262144;
        K = 512; bid &= 255;
    } else {
        in = gW; out = WT + 1048576; K = 1024; bid -= 1024;
    }
    __shared__ float t[32][33];
    int bx = bid & 15, by = bid >> 4;   // N=512 always -> 16 col tiles
    int n0 = bx * 32, k0 = by * 32;
    int tx = threadIdx.x & 31, ty = threadIdx.x >> 5;
    #pragma unroll
    for (int i=0;i<4;i++)
        t[ty + i*8][tx] = in[(size_t)(k0 + ty + i*8) * 512 + n0 + tx];
    __syncthreads();
    #pragma unroll
    for (int i=0;i<4;i++)
        out[(size_t)(n0 + ty + i*8) * K + k0 + tx] = f2bf(t[tx][ty + i*8]);
}

// ---------------------------------------------------------------- unified 128x64-tile GEMM
template<int MODE, int KK>
__global__ __launch_bounds__(256) void gemm_u(
    const short* __restrict__ A, const float* __restrict__ F1, const float* __restrict__ F2,
    const short* __restrict__ WT,
    short* __restrict__ O0, short* __restrict__ O1, short* __restrict__ O2,
    float* __restrict__ FO, const float* __restrict__ bias)
{
    __shared__ short As[128*64];
    __shared__ short Bs[64*64];
    int tid = threadIdx.x;
    int w = tid >> 6, l = tid & 63;
    int lr = l & 15, lg = l >> 4;
    int tn = blockIdx.x & 7, tm = blockIdx.x >> 3;
    int srow = tid >> 3, sslot = tid & 7;

    const short* Bseg = WT;
    if (MODE == 0) {
        int seg = (tm < 32) ? 0 : (tm < 65) ? 1 : 2;   // 4096 | 8320 row boundaries
        Bseg = WT + (size_t)seg * 262144;
    }

    f32x4 acc[2][4];
    #pragma unroll
    for (int m=0;m<2;m++)
        #pragma unroll
        for (int n=0;n<4;n++) acc[m][n] = (f32x4){0.f,0.f,0.f,0.f};

    for (int k0 = 0; k0 < KK; k0 += 64) {
        #pragma unroll
        for (int i=0;i<2;i++){
            int row = i*32 + srow;
            int gslot = sslot ^ (row & 7);
            const short* gb = Bseg + (size_t)(tn*64 + row) * KK + k0 + gslot*8;
            short* lb = Bs + (i*256 + w*64) * 8;
            __builtin_amdgcn_global_load_lds((const __attribute__((address_space(1))) void*)gb,
                                             (__attribute__((address_space(3))) void*)lb, 16, 0, 0);
        }
        if (MODE != 2) {
            #pragma unroll
            for (int i=0;i<4;i++){
                int row = i*32 + srow;
                int gslot = sslot ^ (row & 7);
                const short* ga = A + (size_t)(tm*128 + row) * KK + k0 + gslot*8;
                short* la = As + (i*256 + w*64) * 8;
                __builtin_amdgcn_global_load_lds((const __attribute__((address_space(1))) void*)ga,
                                                 (__attribute__((address_space(3))) void*)la, 16, 0, 0);
            }
        } else {
            const float* src = (k0 < 512) ? F1 : F2;
            int csub = (k0 < 512) ? k0 : k0 - 512;
            #pragma unroll
            for (int i=0;i<4;i++){
                int row = i*32 + srow;
                const float* gp = src + (size_t)(tm*128 + row) * 512 + csub + sslot*8;
                f32x4 a0 = *(const f32x4*)gp;
                f32x4 a1 = *(const f32x4*)(gp + 4);
                s16x8 o;
                #pragma unroll
                for (int t=0;t<4;t++){ o[t] = f2bf(a0[t]); o[t+4] = f2bf(a1[t]); }
                *(s16x8*)(As + row*64 + (sslot ^ (row & 7))*8) = o;
            }
        }
        __syncthreads();
        #pragma unroll
        for (int s=0;s<2;s++){
            s16x8 af[2], bfr[4];
            #pragma unroll
            for (int m=0;m<2;m++){
                int row = w*32 + m*16 + lr;
                int slot = (s*4 + lg) ^ (row & 7);
                af[m] = *(const s16x8*)(As + row*64 + slot*8);
            }
            #pragma unroll
            for (int n=0;n<4;n++){
                int row = n*16 + lr;
                int slot = (s*4 + lg) ^ (row & 7);
                bfr[n] = *(const s16x8*)(Bs + row*64 + slot*8);
            }
            #pragma unroll
            for (int m=0;m<2;m++)
                #pragma unroll
                for (int n=0;n<4;n++)
                    acc[m][n] = __builtin_amdgcn_mfma_f32_16x16x32_bf16(af[m], bfr[n], acc[m][n], 0, 0, 0);
        }
        __syncthreads();
    }

    #pragma unroll
    for (int n=0;n<4;n++){
        int col = tn*64 + n*16 + lr;
        float badd = (MODE == 2) ? bias[col] : 0.0f;
        #pragma unroll
        for (int m=0;m<2;m++){
            #pragma unroll
            for (int j=0;j<4;j++){
                int row = tm*128 + w*32 + m*16 + lg*4 + j;
                float v = acc[m][n][j];
                if (MODE == 0) {
                    short bv = f2bf(v);
                    if (row < 4096) {
                        O0[(size_t)row*512 + col] = bv;
                    } else if (row < 8320) {
                        int r2 = row - 4096;
                        if (r2 < 4160) O1[(size_t)r2*512 + col] = bv;
                    } else {
                        int r2 = row - 8320;
                        if (r2 < 4160) O2[(size_t)r2*512 + col] = bv;
                    }
                } else if (MODE == 1) {
                    FO[(size_t)row*512 + col] = v;
                } else {
                    size_t idx = (size_t)row*512 + col;
                    float g = 1.0f / (1.0f + __expf(-(v + badd)));
                    float q = F1[idx], a = F2[idx];
                    FO[idx] = q + g*q + (1.0f - g)*a;
                }
            }
        }
    }
}

// ---------------------------------------------------------------- vhp -> vhT[b][h][64][KPAD]
__global__ __launch_bounds__(256) void transpose_v(
    const short* __restrict__ vh, short* __restrict__ vhT)
{
    __shared__ short t[64][72];
    int tid = threadIdx.x, bid = blockIdx.x;
    int kt = bid % 33; int hh = (bid / 33) & 7; int b = bid / (33*8);
    int k0 = kt * 64;
    int rr = tid >> 3, c8 = (tid & 7) * 8;
    #pragma unroll
    for (int p=0;p<2;p++){
        int kr = p*32 + rr;
        int gk = k0 + kr;
        s16x8 v = {0,0,0,0,0,0,0,0};
        if (gk < KPAD) v = *(const s16x8*)(vh + (size_t)(b*KPAD + gk)*DMODEL + hh*64 + c8);
        *(s16x8*)&t[kr][c8] = v;
    }
    __syncthreads();
    #pragma unroll
    for (int p=0;p<2;p++){
        int dr = p*32 + rr;
        if (k0 + c8 < KPAD){
            s16x8 o;
            #pragma unroll
            for (int j2=0;j2<8;j2++) o[j2] = t[c8+j2][dr];
            *(s16x8*)(vhT + ((size_t)(b*8 + hh)*64 + dr)*KPAD + k0 + c8) = o;
        }
    }
}

// ---------------------------------------------------------------- flash attention, split-KV 3-way
// bid = ((qblk*3 + split)*2 + b)*8 + h  ->  bid%8 == h: each XCD owns one head.
// Block-cooperative: 4 waves cover 64 q-rows; per 64-key chunk the block stages
// K[64][64] and V[64][64] into LDS once (global_load_lds, pre-swizzled source) —
// 4x vmem dedup vs per-wave loads. 2 barriers/chunk (m97 pattern).
__global__ __launch_bounds__(256, 6) void flash_kernel(
    const short* __restrict__ qh, const short* __restrict__ kh,
    const short* __restrict__ vhT, const float* __restrict__ kbias,
    short* __restrict__ On, float* __restrict__ ml)
{
    __shared__ short Ks[64*64];
    __shared__ short Vs[64*64];
    __shared__ short plds[4][16*72];
    int tid = threadIdx.x;
    int w = tid >> 6, l = tid & 63;
    int bid = blockIdx.x;
    int h = bid & 7;
    int b = (bid >> 3) & 1;
    int t = bid >> 4;            // 0..95
    int qblk = t / 3;
    int split = t - qblk * 3;
    int q0 = qblk * 64 + w * 16;
    int cl = l & 15, rg = l >> 4;
    int srow = tid >> 3, sslot = tid & 7;

    const short* qp = qh + ((size_t)(b*SEQ + q0 + cl))*DMODEL + h*64 + rg*8;
    s16x8 qf0 = *(const s16x8*)qp;
    s16x8 qf1 = *(const s16x8*)(qp + 32);

    f32x4 O[4];
    float mrow[4], lsum[4];
    #pragma unroll
    for (int n=0;n<4;n++) O[n] = (f32x4){0.f,0.f,0.f,0.f};
    #pragma unroll
    for (int j=0;j<4;j++){ mrow[j] = -1e30f; lsum[j] = 0.f; }

    const short* khb = kh + (size_t)b*KPAD*DMODEL + h*64;
    const short* vtb = vhT + (size_t)(b*8 + h)*64*KPAD;
    const float* kbb = kbias + b*KPAD;
    short* pl = plds[w];

    int kc0 = split * 11;
    int kcN = kc0 + ((split == 2) ? 10 : 11);
    for (int kc = kc0; kc < kcN; ++kc) {
        int k0 = kc * 64;
        if (kc > kc0) __syncthreads();   // prev chunk's LDS reads complete
        #pragma unroll
        for (int i=0;i<2;i++){
            int row = i*32 + srow;
            int gslot = sslot ^ (row & 7);
            const short* gk = khb + (size_t)(k0 + row)*DMODEL + gslot*8;
            const short* gv = vtb + (size_t)row*KPAD + k0 + gslot*8;
            short* lk = Ks + (i*256 + w*64)*8;
            short* lv = Vs + (i*256 + w*64)*8;
            __builtin_amdgcn_global_load_lds((const __attribute__((address_space(1))) void*)gk,
                                             (__attribute__((address_space(3))) void*)lk, 16, 0, 0);
            __builtin_amdgcn_global_load_lds((const __attribute__((address_space(1))) void*)gv,
                                             (__attribute__((address_space(3))) void*)lv, 16, 0, 0);
        }
        __syncthreads();                 // staging drained (compiler emits vmcnt(0))

        float sv[4][4];
        #pragma unroll
        for (int nh=0; nh<4; ++nh) {
            int row = nh*16 + cl;
            s16x8 ka  = *(const s16x8*)(Ks + row*64 + ((rg)     ^ (row & 7))*8);
            s16x8 kb2 = *(const s16x8*)(Ks + row*64 + ((4 + rg) ^ (row & 7))*8);
            f32x4 z = (f32x4){0.f,0.f,0.f,0.f};
            z = __builtin_amdgcn_mfma_f32_16x16x32_bf16(qf0, ka,  z, 0, 0, 0);
            z = __builtin_amdgcn_mfma_f32_16x16x32_bf16(qf1, kb2, z, 0, 0, 0);
            float bias = kbb[k0 + nh*16 + cl];
            #pragma unroll
            for (int j=0;j<4;j++) sv[nh][j] = fmaf(z[j], 0.125f, bias);
        }
        float ml4[4];
        #pragma unroll
        for (int j=0;j<4;j++)
            ml4[j] = fmaxf(fmaxf(sv[0][j], sv[1][j]), fmaxf(sv[2][j], sv[3][j]));
        #pragma unroll
        for (int off=1; off<16; off<<=1){
            #pragma unroll
            for (int j=0;j<4;j++) ml4[j] = fmaxf(ml4[j], __shfl_xor(ml4[j], off));
        }
        bool need = (ml4[0] > mrow[0]+8.f) || (ml4[1] > mrow[1]+8.f) ||
                    (ml4[2] > mrow[2]+8.f) || (ml4[3] > mrow[3]+8.f);
        if (__any(need)) {
            #pragma unroll
            for (int j=0;j<4;j++){
                float mn = fmaxf(mrow[j], ml4[j]);
                float sc = __expf(mrow[j] - mn);
                mrow[j] = mn; lsum[j] *= sc;
                #pragma unroll
                for (int n=0;n<4;n++) O[n][j] *= sc;
            }
        }
        float ps[4] = {0.f,0.f,0.f,0.f};
        #pragma unroll
        for (int nh=0; nh<4; ++nh){
            #pragma unroll
            for (int j=0;j<4;j++){
                float p = __expf(sv[nh][j] - mrow[j]);
                ps[j] += p;
                pl[(rg*4 + j)*72 + nh*16 + cl] = f2bf(p);
            }
        }
        #pragma unroll
        for (int off=1; off<16; off<<=1){
            #pragma unroll
            for (int j=0;j<4;j++) ps[j] += __shfl_xor(ps[j], off);
        }
        #pragma unroll
        for (int j=0;j<4;j++) lsum[j] += ps[j];

        s16x8 pa0 = *(const s16x8*)(pl + cl*72 + rg*8);
        s16x8 pa1 = *(const s16x8*)(pl + cl*72 + 32 + rg*8);
        __builtin_amdgcn_s_setprio(1);
        #pragma unroll
        for (int n=0;n<4;n++){
            int row = n*16 + cl;
            s16x8 vf0 = *(const s16x8*)(Vs + row*64 + ((rg)     ^ (row & 7))*8);
            s16x8 vf1 = *(const s16x8*)(Vs + row*64 + ((4 + rg) ^ (row & 7))*8);
            O[n] = __builtin_amdgcn_mfma_f32_16x16x32_bf16(pa0, vf0, O[n], 0, 0, 0);
            O[n] = __builtin_amdgcn_mfma_f32_16x16x32_bf16(pa1, vf1, O[n], 0, 0, 0);
        }
        __builtin_amdgcn_s_setprio(0);
    }

    if (split == 2) {  // tail: keys 2048..2079, global-direct (one 32-key chunk)
        int k0 = 2048;
        float sv[2][4];
        #pragma unroll
        for (int nh=0; nh<2; ++nh) {
            const short* kp = khb + (size_t)(k0 + nh*16 + cl)*DMODEL + rg*8;
            s16x8 ka = *(const s16x8*)kp;
            s16x8 kb2 = *(const s16x8*)(kp + 32);
            f32x4 z = (f32x4){0.f,0.f,0.f,0.f};
            z = __builtin_amdgcn_mfma_f32_16x16x32_bf16(qf0, ka,  z, 0, 0, 0);
            z = __builtin_amdgcn_mfma_f32_16x16x32_bf16(qf1, kb2, z, 0, 0, 0);
            float bias = kbb[k0 + nh*16 + cl];
            #pragma unroll
            for (int j=0;j<4;j++) sv[nh][j] = fmaf(z[j], 0.125f, bias);
        }
        float ml4[4];
        #pragma unroll
        for (int j=0;j<4;j++) ml4[j] = fmaxf(sv[0][j], sv[1][j]);
        #pragma unroll
        for (int off=1; off<16; off<<=1){
            #pragma unroll
            for (int j=0;j<4;j++) ml4[j] = fmaxf(ml4[j], __shfl_xor(ml4[j], off));
        }
        bool need = (ml4[0] > mrow[0]+8.f) || (ml4[1] > mrow[1]+8.f) ||
                    (ml4[2] > mrow[2]+8.f) || (ml4[3] > mrow[3]+8.f);
        if (__any(need)) {
            #pragma unroll
            for (int j=0;j<4;j++){
                float mn = fmaxf(mrow[j], ml4[j]);
                float sc = __expf(mrow[j] - mn);
                mrow[j] = mn; lsum[j] *= sc;
                #pragma unroll
                for (int n=0;n<4;n++) O[n][j] *= sc;
            }
        }
        float ps[4] = {0.f,0.f,0.f,0.f};
        #pragma unroll
        for (int nh=0; nh<2; ++nh){
            #pragma unroll
            for (int j=0;j<4;j++){
                float p = __expf(sv[nh][j] - mrow[j]);
                ps[j] += p;
                pl[(rg*4 + j)*72 + nh*16 + cl] = f2bf(p);
            }
        }
        #pragma unroll
        for (int off=1; off<16; off<<=1){
            #pragma unroll
            for (int j=0;j<4;j++) ps[j] += __shfl_xor(ps[j], off);
        }
        #pragma unroll
        for (int j=0;j<4;j++) lsum[j] += ps[j];

        s16x8 pa0 = *(const s16x8*)(pl + cl*72 + rg*8);
        __builtin_amdgcn_s_setprio(1);
        #pragma unroll
        for (int n=0;n<4;n++){
            s16x8 vf0 = *(const s16x8*)(vtb + (size_t)(n*16 + cl)*KPAD + k0 + rg*8);
            O[n] = __builtin_amdgcn_mfma_f32_16x16x32_bf16(pa0, vf0, O[n], 0, 0, 0);
        }
        __builtin_amdgcn_s_setprio(0);
    }

    // store normalized partial + (m, l)
    int rbase = ((b*8 + h) << 11) + q0;
    #pragma unroll
    for (int j=0;j<4;j++){
        int r = rbase + rg*4 + j;
        float invl = 1.0f / lsum[j];
        #pragma unroll
        for (int n=0;n<4;n++)
            On[((size_t)split*NROWS + r)*64 + n*16 + cl] = f2bf(O[n][j] * invl);
        if (cl == 0){
            ml[((size_t)split*NROWS + r)*2    ] = mrow[j];
            ml[((size_t)split*NROWS + r)*2 + 1] = lsum[j];
        }
    }
}

// ---------------------------------------------------------------- merge 3 split-KV partials -> av bf16
__global__ __launch_bounds__(256) void merge_kernel(
    const short* __restrict__ On, const float* __restrict__ ml,
    const int* __restrict__ qmask, short* __restrict__ av)
{
    int tid = threadIdx.x;
    int r = blockIdx.x * 32 + (tid >> 3);
    int d8 = (tid & 7) * 8;
    float m0 = ml[(size_t)r*2],              l0 = ml[(size_t)r*2 + 1];
    float m1 = ml[((size_t)NROWS + r)*2],    l1 = ml[((size_t)NROWS + r)*2 + 1];
    float m2 = ml[((size_t)2*NROWS + r)*2],  l2 = ml[((size_t)2*NROWS + r)*2 + 1];
    float m = fmaxf(m0, fmaxf(m1, m2));
    float w0 = l0 * __expf(m0 - m), w1 = l1 * __expf(m1 - m), w2 = l2 * __expf(m2 - m);
    int qrow = r & 2047, bh = r >> 11, h = bh & 7, b = bh >> 3;
    int qm = qmask[b*SEQ + qrow];
    float inv = qm ? 1.0f / (w0 + w1 + w2) : 0.0f;
    w0 *= inv; w1 *= inv; w2 *= inv;
    s16x8 o0 = *(const s16x8*)(On + (size_t)r*64 + d8);
    s16x8 o1 = *(const s16x8*)(On + ((size_t)NROWS + r)*64 + d8);
    s16x8 o2 = *(const s16x8*)(On + ((size_t)2*NROWS + r)*64 + d8);
    s16x8 o;
    #pragma unroll
    for (int e=0;e<8;e++) o[e] = f2bf(w0*bf2f(o0[e]) + w1*bf2f(o1[e]) + w2*bf2f(o2[e]));
    *(s16x8*)(av + ((size_t)(b*SEQ + qrow))*DMODEL + h*64 + d8) = o;
}

// ---------------------------------------------------------------- launch
extern "C" void kernel_launch(void* const* d_in, const int* in_sizes, int n_in,
                              void* d_out, int out_size, void* d_ws, size_t ws_size,
                              hipStream_t stream)
{
    const float* query = (const float*)d_in[0];
    const float* key   = (const float*)d_in[1];
    const float* value = (const float*)d_in[2];
    const float* Wq    = (const float*)d_in[3];
    const float* Wk    = (const float*)d_in[4];
    const float* Wv    = (const float*)d_in[5];
    const float* Wo    = (const float*)d_in[6];
    const float* gW    = (const float*)d_in[7];
    const float* gB    = (const float*)d_in[8];
    const float* qg    = (const float*)d_in[9];
    const float* qb    = (const float*)d_in[10];
    const float* kg    = (const float*)d_in[11];
    const float* kb    = (const float*)d_in[12];
    const float* vg    = (const float*)d_in[13];
    const float* vb    = (const float*)d_in[14];
    const int* qmask   = (const int*)d_in[15];
    const int* kmask   = (const int*)d_in[16];
    float* out = (float*)d_out;
    char* ws = (char*)d_ws;

    if (ws_size < WS_NEEDED) return;

    short* qn  = (short*)(ws + OFF_QN);
    short* kn  = (short*)(ws + OFF_KN);
    short* vn  = (short*)(ws + OFF_VN);
    short* qh  = (short*)(ws + OFF_QH);
    short* khp = (short*)(ws + OFF_KH);
    short* vhp = (short*)(ws + OFF_VH);
    short* vhT = (short*)(ws + OFF_VHT);
    short* av  = (short*)(ws + OFF_AV);
    short* WT  = (short*)(ws + OFF_WQT);
    short* WoT = WT + 3*262144;
    short* gWT = WT + 1048576;
    short* On  = (short*)(ws + OFF_ON);
    float* mlp = (float*)(ws + OFF_ML);
    float* kbp = (float*)(ws + OFF_KB);
    float* ap  = (float*)(ws + OFF_AP);

    // 1. layernorm + cast (kn/vn zero-padded to 4224 rows)
    ln_all<<<3136, 256, 0, stream>>>(query, key, value, qg, qb, kg, kb, vg, vb, qn, kn, vn);

    // 2. all weights -> bf16 transposed + kbias
    wt_all<<<1553, 256, 0, stream>>>(Wq, Wk, Wv, Wo, gW, WT, kmask, kbp);

    // 3. fused QKV projection, 128x64 tiles
    gemm_u<0,512><<<784, 256, 0, stream>>>(qn, nullptr, nullptr, WT, qh, khp, vhp, nullptr, nullptr);

    // 4. V transpose for PV MFMA B-operand
    transpose_v<<<528, 256, 0, stream>>>(vhp, vhT);

    // 5. flash attention, split-KV 3-way, XCD-local heads, LDS-staged K/V
    flash_kernel<<<1536, 256, 0, stream>>>(qh, khp, vhT, kbp, On, mlp);
    merge_kernel<<<1024, 256, 0, stream>>>(On, mlp, qmask, av);

    // 6. output projection (f32 out)
    gemm_u<1,512><<<256, 256, 0, stream>>>(av, nullptr, nullptr, WoT, nullptr, nullptr, nullptr, ap, nullptr);

    // 7. gate GEMM fused: concat-stage + sigmoid + residual
    gemm_u<2,1024><<<256, 256, 0, stream>>>(nullptr, query, ap, gWT, nullptr, nullptr, nullptr, out, gB);

    (void)in_sizes; (void)n_in; (void)out_size;
}

// Round 9
// 231.393 us; speedup vs baseline: 1.4186x; 1.0381x over previous
//
#include <hip/hip_runtime.h>

typedef float f32x4 __attribute__((ext_vector_type(4)));
typedef short s16x8 __attribute__((ext_vector_type(8)));

#define DEV __device__ __forceinline__

DEV short f2bf(float f) {
    union { float f; unsigned u; } v; v.f = f;
    unsigned r = v.u + 0x7fffu + ((v.u >> 16) & 1u);
    return (short)(r >> 16);
}
DEV float bf2f(short s) {
    union { unsigned u; float f; } v; v.u = ((unsigned)(unsigned short)s) << 16;
    return v.f;
}

// B=2, Q=K=2048, D=512, H=8, hd=64. KV padded: 2048 real + 1 zero-attn + 31 pad = 2080
#define SEQ    2048
#define DMODEL 512
#define KPAD   2080
#define NROWS  32768   /* B*H*SEQ flash output rows */

// ws layout (bytes). qn|kn|vn contiguous (A of the single QKV GEMM), weights contiguous.
#define OFF_QN   0ull            /* 4096 rows = 4,194,304 */
#define OFF_KN   4194304ull      /* 4160 rows = 4,259,840 */
#define OFF_VN   8454144ull      /* 4160 rows -> ends 12,713,984 */
#define OFF_QH   12845056ull     /* 4,194,304 */
#define OFF_KH   17039360ull     /* 4,259,840 -> ends 21,299,200 */
#define OFF_VH   21364736ull     /* vhp 4,259,840 -> ends 25,624,576 */
#define OFF_VHT  25690112ull     /* 4,259,840 -> ends 29,949,952 */
#define OFF_KB   29949952ull     /* key bias f32 2*2080*4 = 16,640 */
#define OFF_ML   29966592ull     /* (m,l) f32 [3][32768][2] = 786,432 -> ends 30,753,024 */
#define OFF_WQT  34144256ull     /* WqT|WkT|WvT|WoT|gWT = 4*524,288 + 1,048,576 */
#define WS_NEEDED 37289984ull
// aliased (lifetimes disjoint):
#define OFF_ON   0ull            /* flash partials bf16 [3][32768][64] = 12,582,912 over qn|kn|vn (dead post-qkv) */
#define OFF_AP   17039360ull     /* attn_proj f32 8,388,608 over kh+vhp (dead post-flash/transpose) */

// ---------------------------------------------------------------- fused prep: LN(q,k,v) + weight transpose + kbias
// bid 0..3103: layernorm rows; 3104..4639: weight 32x32 transpose tiles; 4640..4656: kbias
__global__ __launch_bounds__(256) void prep_all(
    const float* __restrict__ q, const float* __restrict__ k, const float* __restrict__ v,
    const float* __restrict__ qg, const float* __restrict__ qb,
    const float* __restrict__ kg, const float* __restrict__ kb2,
    const float* __restrict__ vg, const float* __restrict__ vb,
    const float* __restrict__ Wq, const float* __restrict__ Wk,
    const float* __restrict__ Wv, const float* __restrict__ Wo,
    const float* __restrict__ gW, const int* __restrict__ km,
    short* __restrict__ qn, short* __restrict__ kn, short* __restrict__ vn,
    short* __restrict__ WT, float* __restrict__ kbias)
{
    int bid = blockIdx.x;
    if (bid < 3104) {
        const float *in, *gamma, *beta; short* out; int Spad;
        if (bid < 1024)      { in=q; gamma=qg; beta=qb;  out=qn; Spad=SEQ;  }
        else if (bid < 2064) { bid-=1024; in=k; gamma=kg; beta=kb2; out=kn; Spad=KPAD; }
        else                 { bid-=2064; in=v; gamma=vg; beta=vb;  out=vn; Spad=KPAD; }

        int w = threadIdx.x >> 6, l = threadIdx.x & 63;
        int r = bid * 4 + w;
        short* op = out + (size_t)r * DMODEL + l * 8;
        s16x8 o = {0,0,0,0,0,0,0,0};
        int b = r / Spad, j = r - b * Spad;
        if (j >= SEQ) {
            if (j == SEQ) {
                f32x4 b0 = *(const f32x4*)(beta + l*8);
                f32x4 b1 = *(const f32x4*)(beta + l*8 + 4);
                #pragma unroll
                for (int t=0;t<4;t++){ o[t]=f2bf(b0[t]); o[t+4]=f2bf(b1[t]); }
            }
            *(s16x8*)op = o; return;
        }
        const float* ip = in + ((size_t)b * SEQ + j) * DMODEL + l * 8;
        f32x4 x0 = *(const f32x4*)ip;
        f32x4 x1 = *(const f32x4*)(ip + 4);
        float s = x0[0]+x0[1]+x0[2]+x0[3]+x1[0]+x1[1]+x1[2]+x1[3];
        #pragma unroll
        for (int off=1; off<64; off<<=1) s += __shfl_xor(s, off);
        float mean = s * (1.0f/512.0f);
        float vs = 0.f;
        #pragma unroll
        for (int t=0;t<4;t++){ float d0=x0[t]-mean, d1=x1[t]-mean; vs += d0*d0 + d1*d1; }
        #pragma unroll
        for (int off=1; off<64; off<<=1) vs += __shfl_xor(vs, off);
        float rstd = rsqrtf(vs * (1.0f/512.0f) + 1e-5f);
        f32x4 g0 = *(const f32x4*)(gamma + l*8), g1 = *(const f32x4*)(gamma + l*8 + 4);
        f32x4 b0 = *(const f32x4*)(beta + l*8),  b1 = *(const f32x4*)(beta + l*8 + 4);
        #pragma unroll
        for (int t=0;t<4;t++){
            o[t]   = f2bf((x0[t]-mean)*rstd*g0[t] + b0[t]);
            o[t+4] = f2bf((x1[t]-mean)*rstd*g1[t] + b1[t]);
        }
        *(s16x8*)op = o;
        return;
    }
    bid -= 3104;
    if (bid >= 1536) {
        int i = (bid - 1536) * 256 + threadIdx.x;
        if (i >= 2 * KPAD) return;
        int b = i / KPAD, j = i - b * KPAD;
        float val;
        if (j < SEQ)       val = km[b*SEQ + j] ? 0.0f : -1e30f;
        else if (j == SEQ) val = 0.0f;     // zero-attn slot (mask bit 1)
        else               val = -1e30f;   // pad rows
        kbias[i] = val;
        return;
    }
    const float* in; short* out; int K;
    if (bid < 1024) {
        int wsel = bid >> 8;
        in = (wsel==0) ? Wq : (wsel==1) ? Wk : (wsel==2) ? Wv : Wo;
        out = WT + (size_t)wsel * 262144;
        K = 512; bid &= 255;
    } else {
        in = gW; out = WT + 1048576; K = 1024; bid -= 1024;
    }
    __shared__ float t[32][33];
    int bx = bid & 15, by = bid >> 4;
    int n0 = bx * 32, k0 = by * 32;
    int tx = threadIdx.x & 31, ty = threadIdx.x >> 5;
    #pragma unroll
    for (int i=0;i<4;i++)
        t[ty + i*8][tx] = in[(size_t)(k0 + ty + i*8) * 512 + n0 + tx];
    __syncthreads();
    #pragma unroll
    for (int i=0;i<4;i++)
        out[(size_t)(n0 + ty + i*8) * K + k0 + tx] = f2bf(t[tx][ty + i*8]);
}

// ---------------------------------------------------------------- unified 64x64-tile GEMM (4 waves, acc 2x2)
// MODE 0: qkv — A bf16 (12416,512) via global_load_lds, B seg by row range, 3 bf16 outs.
// MODE 1: Wo with fused split-KV merge — A staged from On/ml/qmask (merged bf16), f32 out.
// MODE 2: gate — A = concat(query, ap) f32 staged->bf16, sigmoid-gate+residual epilogue.
template<int MODE, int KK>
__global__ __launch_bounds__(256) void gemm64(
    const short* __restrict__ A, const float* __restrict__ F1, const float* __restrict__ F2,
    const short* __restrict__ WT,
    short* __restrict__ O0, short* __restrict__ O1, short* __restrict__ O2,
    float* __restrict__ FO, const float* __restrict__ bias,
    const short* __restrict__ On, const float* __restrict__ mlp, const int* __restrict__ qmask)
{
    __shared__ short As[64*64];
    __shared__ short Bs[64*64];
    int tid = threadIdx.x;
    int w = tid >> 6, l = tid & 63;
    int lr = l & 15, lg = l >> 4;
    int tm = blockIdx.x >> 3, tn = blockIdx.x & 7;
    int wm = w >> 1, wn = w & 1;
    int srow = tid >> 3, sslot = tid & 7;

    const short* Bseg = WT;
    if (MODE == 0) {
        int seg = (tm < 64) ? 0 : (tm < 129) ? 1 : 2;   // rows 4096 | 8256 boundaries
        Bseg = WT + (size_t)seg * 262144;
    }

    f32x4 acc[2][2];
    #pragma unroll
    for (int m=0;m<2;m++)
        #pragma unroll
        for (int n=0;n<2;n++) acc[m][n] = (f32x4){0.f,0.f,0.f,0.f};

    for (int k0 = 0; k0 < KK; k0 += 64) {
        // B staging
        #pragma unroll
        for (int i=0;i<2;i++){
            int row = i*32 + srow;
            int gslot = sslot ^ (row & 7);
            const short* gb = Bseg + (size_t)(tn*64 + row) * KK + k0 + gslot*8;
            short* lb = Bs + (i*256 + w*64) * 8;
            __builtin_amdgcn_global_load_lds((const __attribute__((address_space(1))) void*)gb,
                                             (__attribute__((address_space(3))) void*)lb, 16, 0, 0);
        }
        // A staging
        if (MODE == 0) {
            #pragma unroll
            for (int i=0;i<2;i++){
                int row = i*32 + srow;
                int gslot = sslot ^ (row & 7);
                const short* ga = A + (size_t)(tm*64 + row) * KK + k0 + gslot*8;
                short* la = As + (i*256 + w*64) * 8;
                __builtin_amdgcn_global_load_lds((const __attribute__((address_space(1))) void*)ga,
                                                 (__attribute__((address_space(3))) void*)la, 16, 0, 0);
            }
        } else if (MODE == 1) {
            int h = k0 >> 6;   // A col-chunk = head h; merge weights depend on (b,h,qrow)
            #pragma unroll
            for (int i=0;i<2;i++){
                int row = i*32 + srow;
                int r = tm*64 + row;
                int b = r >> 11, qrow = r & 2047;
                int rr = ((b*8 + h) << 11) + qrow;
                float m0 = mlp[(size_t)rr*2],               l0 = mlp[(size_t)rr*2 + 1];
                float m1 = mlp[((size_t)NROWS + rr)*2],     l1 = mlp[((size_t)NROWS + rr)*2 + 1];
                float m2 = mlp[((size_t)2*NROWS + rr)*2],   l2 = mlp[((size_t)2*NROWS + rr)*2 + 1];
                float mm = fmaxf(m0, fmaxf(m1, m2));
                float w0 = l0 * __expf(m0 - mm), w1 = l1 * __expf(m1 - mm), w2 = l2 * __expf(m2 - mm);
                float inv = qmask[b*SEQ + qrow] ? 1.0f / (w0 + w1 + w2) : 0.0f;
                w0 *= inv; w1 *= inv; w2 *= inv;
                s16x8 o0 = *(const s16x8*)(On + ((size_t)rr)*64 + sslot*8);
                s16x8 o1 = *(const s16x8*)(On + ((size_t)NROWS + rr)*64 + sslot*8);
                s16x8 o2 = *(const s16x8*)(On + ((size_t)2*NROWS + rr)*64 + sslot*8);
                s16x8 om;
                #pragma unroll
                for (int e=0;e<8;e++) om[e] = f2bf(w0*bf2f(o0[e]) + w1*bf2f(o1[e]) + w2*bf2f(o2[e]));
                *(s16x8*)(As + row*64 + (sslot ^ (row & 7))*8) = om;
            }
        } else {
            const float* src = (k0 < 512) ? F1 : F2;
            int csub = (k0 < 512) ? k0 : k0 - 512;
            #pragma unroll
            for (int i=0;i<2;i++){
                int row = i*32 + srow;
                const float* gp = src + (size_t)(tm*64 + row) * 512 + csub + sslot*8;
                f32x4 a0 = *(const f32x4*)gp;
                f32x4 a1 = *(const f32x4*)(gp + 4);
                s16x8 o;
                #pragma unroll
                for (int t=0;t<4;t++){ o[t] = f2bf(a0[t]); o[t+4] = f2bf(a1[t]); }
                *(s16x8*)(As + row*64 + (sslot ^ (row & 7))*8) = o;
            }
        }
        __syncthreads();
        #pragma unroll
        for (int s=0;s<2;s++){
            s16x8 af[2], bfr[2];
            #pragma unroll
            for (int m=0;m<2;m++){
                int row = wm*32 + m*16 + lr;
                int slot = (s*4 + lg) ^ (row & 7);
                af[m] = *(const s16x8*)(As + row*64 + slot*8);
            }
            #pragma unroll
            for (int n=0;n<2;n++){
                int row = wn*32 + n*16 + lr;
                int slot = (s*4 + lg) ^ (row & 7);
                bfr[n] = *(const s16x8*)(Bs + row*64 + slot*8);
            }
            #pragma unroll
            for (int m=0;m<2;m++)
                #pragma unroll
                for (int n=0;n<2;n++)
                    acc[m][n] = __builtin_amdgcn_mfma_f32_16x16x32_bf16(af[m], bfr[n], acc[m][n], 0, 0, 0);
        }
        __syncthreads();
    }

    #pragma unroll
    for (int n=0;n<2;n++){
        int col = tn*64 + wn*32 + n*16 + lr;
        float badd = (MODE == 2) ? bias[col] : 0.0f;
        #pragma unroll
        for (int m=0;m<2;m++){
            #pragma unroll
            for (int j=0;j<4;j++){
                int row = tm*64 + wm*32 + m*16 + lg*4 + j;
                float v = acc[m][n][j];
                if (MODE == 0) {
                    short bv = f2bf(v);
                    if (row < 4096)      O0[(size_t)row*512 + col] = bv;
                    else if (row < 8256) O1[(size_t)(row - 4096)*512 + col] = bv;
                    else                 O2[(size_t)(row - 8256)*512 + col] = bv;
                } else if (MODE == 1) {
                    FO[(size_t)row*512 + col] = v;
                } else {
                    size_t idx = (size_t)row*512 + col;
                    float g = 1.0f / (1.0f + __expf(-(v + badd)));
                    float qv = F1[idx], a = F2[idx];
                    FO[idx] = qv + g*qv + (1.0f - g)*a;
                }
            }
        }
    }
}

// ---------------------------------------------------------------- vhp -> vhT[b][h][64][KPAD]
__global__ __launch_bounds__(256) void transpose_v(
    const short* __restrict__ vh, short* __restrict__ vhT)
{
    __shared__ short t[64][72];
    int tid = threadIdx.x, bid = blockIdx.x;
    int kt = bid % 33; int hh = (bid / 33) & 7; int b = bid / (33*8);
    int k0 = kt * 64;
    int rr = tid >> 3, c8 = (tid & 7) * 8;
    #pragma unroll
    for (int p=0;p<2;p++){
        int kr = p*32 + rr;
        int gk = k0 + kr;
        s16x8 v = {0,0,0,0,0,0,0,0};
        if (gk < KPAD) v = *(const s16x8*)(vh + (size_t)(b*KPAD + gk)*DMODEL + hh*64 + c8);
        *(s16x8*)&t[kr][c8] = v;
    }
    __syncthreads();
    #pragma unroll
    for (int p=0;p<2;p++){
        int dr = p*32 + rr;
        if (k0 + c8 < KPAD){
            s16x8 o;
            #pragma unroll
            for (int j2=0;j2<8;j2++) o[j2] = t[c8+j2][dr];
            *(s16x8*)(vhT + ((size_t)(b*8 + hh)*64 + dr)*KPAD + k0 + c8) = o;
        }
    }
}

// ---------------------------------------------------------------- flash attention, split-KV 3-way
// bid%8 == h: each XCD owns one head. Block-cooperative LDS staging of K/V (r8, verified).
__global__ __launch_bounds__(256, 6) void flash_kernel(
    const short* __restrict__ qh, const short* __restrict__ kh,
    const short* __restrict__ vhT, const float* __restrict__ kbias,
    short* __restrict__ On, float* __restrict__ ml)
{
    __shared__ short Ks[64*64];
    __shared__ short Vs[64*64];
    __shared__ short plds[4][16*72];
    int tid = threadIdx.x;
    int w = tid >> 6, l = tid & 63;
    int bid = blockIdx.x;
    int h = bid & 7;
    int b = (bid >> 3) & 1;
    int t = bid >> 4;            // 0..95
    int qblk = t / 3;
    int split = t - qblk * 3;
    int q0 = qblk * 64 + w * 16;
    int cl = l & 15, rg = l >> 4;
    int srow = tid >> 3, sslot = tid & 7;

    const short* qp = qh + ((size_t)(b*SEQ + q0 + cl))*DMODEL + h*64 + rg*8;
    s16x8 qf0 = *(const s16x8*)qp;
    s16x8 qf1 = *(const s16x8*)(qp + 32);

    f32x4 O[4];
    float mrow[4], lsum[4];
    #pragma unroll
    for (int n=0;n<4;n++) O[n] = (f32x4){0.f,0.f,0.f,0.f};
    #pragma unroll
    for (int j=0;j<4;j++){ mrow[j] = -1e30f; lsum[j] = 0.f; }

    const short* khb = kh + (size_t)b*KPAD*DMODEL + h*64;
    const short* vtb = vhT + (size_t)(b*8 + h)*64*KPAD;
    const float* kbb = kbias + b*KPAD;
    short* pl = plds[w];

    int kc0 = split * 11;
    int kcN = kc0 + ((split == 2) ? 10 : 11);
    for (int kc = kc0; kc < kcN; ++kc) {
        int k0 = kc * 64;
        if (kc > kc0) __syncthreads();
        #pragma unroll
        for (int i=0;i<2;i++){
            int row = i*32 + srow;
            int gslot = sslot ^ (row & 7);
            const short* gk = khb + (size_t)(k0 + row)*DMODEL + gslot*8;
            const short* gv = vtb + (size_t)row*KPAD + k0 + gslot*8;
            short* lk = Ks + (i*256 + w*64)*8;
            short* lv = Vs + (i*256 + w*64)*8;
            __builtin_amdgcn_global_load_lds((const __attribute__((address_space(1))) void*)gk,
                                             (__attribute__((address_space(3))) void*)lk, 16, 0, 0);
            __builtin_amdgcn_global_load_lds((const __attribute__((address_space(1))) void*)gv,
                                             (__attribute__((address_space(3))) void*)lv, 16, 0, 0);
        }
        __syncthreads();

        float sv[4][4];
        #pragma unroll
        for (int nh=0; nh<4; ++nh) {
            int row = nh*16 + cl;
            s16x8 ka  = *(const s16x8*)(Ks + row*64 + ((rg)     ^ (row & 7))*8);
            s16x8 kb2 = *(const s16x8*)(Ks + row*64 + ((4 + rg) ^ (row & 7))*8);
            f32x4 z = (f32x4){0.f,0.f,0.f,0.f};
            z = __builtin_amdgcn_mfma_f32_16x16x32_bf16(qf0, ka,  z, 0, 0, 0);
            z = __builtin_amdgcn_mfma_f32_16x16x32_bf16(qf1, kb2, z, 0, 0, 0);
            float bias = kbb[k0 + nh*16 + cl];
            #pragma unroll
            for (int j=0;j<4;j++) sv[nh][j] = fmaf(z[j], 0.125f, bias);
        }
        float ml4[4];
        #pragma unroll
        for (int j=0;j<4;j++)
            ml4[j] = fmaxf(fmaxf(sv[0][j], sv[1][j]), fmaxf(sv[2][j], sv[3][j]));
        #pragma unroll
        for (int off=1; off<16; off<<=1){
            #pragma unroll
            for (int j=0;j<4;j++) ml4[j] = fmaxf(ml4[j], __shfl_xor(ml4[j], off));
        }
        bool need = (ml4[0] > mrow[0]+8.f) || (ml4[1] > mrow[1]+8.f) ||
                    (ml4[2] > mrow[2]+8.f) || (ml4[3] > mrow[3]+8.f);
        if (__any(need)) {
            #pragma unroll
            for (int j=0;j<4;j++){
                float mn = fmaxf(mrow[j], ml4[j]);
                float sc = __expf(mrow[j] - mn);
                mrow[j] = mn; lsum[j] *= sc;
                #pragma unroll
                for (int n=0;n<4;n++) O[n][j] *= sc;
            }
        }
        float ps[4] = {0.f,0.f,0.f,0.f};
        #pragma unroll
        for (int nh=0; nh<4; ++nh){
            #pragma unroll
            for (int j=0;j<4;j++){
                float p = __expf(sv[nh][j] - mrow[j]);
                ps[j] += p;
                pl[(rg*4 + j)*72 + nh*16 + cl] = f2bf(p);
            }
        }
        #pragma unroll
        for (int off=1; off<16; off<<=1){
            #pragma unroll
            for (int j=0;j<4;j++) ps[j] += __shfl_xor(ps[j], off);
        }
        #pragma unroll
        for (int j=0;j<4;j++) lsum[j] += ps[j];

        s16x8 pa0 = *(const s16x8*)(pl + cl*72 + rg*8);
        s16x8 pa1 = *(const s16x8*)(pl + cl*72 + 32 + rg*8);
        __builtin_amdgcn_s_setprio(1);
        #pragma unroll
        for (int n=0;n<4;n++){
            int row = n*16 + cl;
            s16x8 vf0 = *(const s16x8*)(Vs + row*64 + ((rg)     ^ (row & 7))*8);
            s16x8 vf1 = *(const s16x8*)(Vs + row*64 + ((4 + rg) ^ (row & 7))*8);
            O[n] = __builtin_amdgcn_mfma_f32_16x16x32_bf16(pa0, vf0, O[n], 0, 0, 0);
            O[n] = __builtin_amdgcn_mfma_f32_16x16x32_bf16(pa1, vf1, O[n], 0, 0, 0);
        }
        __builtin_amdgcn_s_setprio(0);
    }

    if (split == 2) {  // tail: keys 2048..2079, global-direct
        int k0 = 2048;
        float sv[2][4];
        #pragma unroll
        for (int nh=0; nh<2; ++nh) {
            const short* kp = khb + (size_t)(k0 + nh*16 + cl)*DMODEL + rg*8;
            s16x8 ka = *(const s16x8*)kp;
            s16x8 kb2 = *(const s16x8*)(kp + 32);
            f32x4 z = (f32x4){0.f,0.f,0.f,0.f};
            z = __builtin_amdgcn_mfma_f32_16x16x32_bf16(qf0, ka,  z, 0, 0, 0);
            z = __builtin_amdgcn_mfma_f32_16x16x32_bf16(qf1, kb2, z, 0, 0, 0);
            float bias = kbb[k0 + nh*16 + cl];
            #pragma unroll
            for (int j=0;j<4;j++) sv[nh][j] = fmaf(z[j], 0.125f, bias);
        }
        float ml4[4];
        #pragma unroll
        for (int j=0;j<4;j++) ml4[j] = fmaxf(sv[0][j], sv[1][j]);
        #pragma unroll
        for (int off=1; off<16; off<<=1){
            #pragma unroll
            for (int j=0;j<4;j++) ml4[j] = fmaxf(ml4[j], __shfl_xor(ml4[j], off));
        }
        bool need = (ml4[0] > mrow[0]+8.f) || (ml4[1] > mrow[1]+8.f) ||
                    (ml4[2] > mrow[2]+8.f) || (ml4[3] > mrow[3]+8.f);
        if (__any(need)) {
            #pragma unroll
            for (int j=0;j<4;j++){
                float mn = fmaxf(mrow[j], ml4[j]);
                float sc = __expf(mrow[j] - mn);
                mrow[j] = mn; lsum[j] *= sc;
                #pragma unroll
                for (int n=0;n<4;n++) O[n][j] *= sc;
            }
        }
        float ps[4] = {0.f,0.f,0.f,0.f};
        #pragma unroll
        for (int nh=0; nh<2; ++nh){
            #pragma unroll
            for (int j=0;j<4;j++){
                float p = __expf(sv[nh][j] - mrow[j]);
                ps[j] += p;
                pl[(rg*4 + j)*72 + nh*16 + cl] = f2bf(p);
            }
        }
        #pragma unroll
        for (int off=1; off<16; off<<=1){
            #pragma unroll
            for (int j=0;j<4;j++) ps[j] += __shfl_xor(ps[j], off);
        }
        #pragma unroll
        for (int j=0;j<4;j++) lsum[j] += ps[j];

        s16x8 pa0 = *(const s16x8*)(pl + cl*72 + rg*8);
        __builtin_amdgcn_s_setprio(1);
        #pragma unroll
        for (int n=0;n<4;n++){
            s16x8 vf0 = *(const s16x8*)(vtb + (size_t)(n*16 + cl)*KPAD + k0 + rg*8);
            O[n] = __builtin_amdgcn_mfma_f32_16x16x32_bf16(pa0, vf0, O[n], 0, 0, 0);
        }
        __builtin_amdgcn_s_setprio(0);
    }

    // store normalized partial + (m, l)
    int rbase = ((b*8 + h) << 11) + q0;
    #pragma unroll
    for (int j=0;j<4;j++){
        int r = rbase + rg*4 + j;
        float invl = 1.0f / lsum[j];
        #pragma unroll
        for (int n=0;n<4;n++)
            On[((size_t)split*NROWS + r)*64 + n*16 + cl] = f2bf(O[n][j] * invl);
        if (cl == 0){
            ml[((size_t)split*NROWS + r)*2    ] = mrow[j];
            ml[((size_t)split*NROWS + r)*2 + 1] = lsum[j];
        }
    }
}

// ---------------------------------------------------------------- launch
extern "C" void kernel_launch(void* const* d_in, const int* in_sizes, int n_in,
                              void* d_out, int out_size, void* d_ws, size_t ws_size,
                              hipStream_t stream)
{
    const float* query = (const float*)d_in[0];
    const float* key   = (const float*)d_in[1];
    const float* value = (const float*)d_in[2];
    const float* Wq    = (const float*)d_in[3];
    const float* Wk    = (const float*)d_in[4];
    const float* Wv    = (const float*)d_in[5];
    const float* Wo    = (const float*)d_in[6];
    const float* gW    = (const float*)d_in[7];
    const float* gB    = (const float*)d_in[8];
    const float* qg    = (const float*)d_in[9];
    const float* qb    = (const float*)d_in[10];
    const float* kg    = (const float*)d_in[11];
    const float* kb    = (const float*)d_in[12];
    const float* vg    = (const float*)d_in[13];
    const float* vb    = (const float*)d_in[14];
    const int* qmask   = (const int*)d_in[15];
    const int* kmask   = (const int*)d_in[16];
    float* out = (float*)d_out;
    char* ws = (char*)d_ws;

    if (ws_size < WS_NEEDED) return;

    short* qn  = (short*)(ws + OFF_QN);
    short* kn  = (short*)(ws + OFF_KN);
    short* vn  = (short*)(ws + OFF_VN);
    short* qh  = (short*)(ws + OFF_QH);
    short* khp = (short*)(ws + OFF_KH);
    short* vhp = (short*)(ws + OFF_VH);
    short* vhT = (short*)(ws + OFF_VHT);
    short* WT  = (short*)(ws + OFF_WQT);
    short* WoT = WT + 3*262144;
    short* gWT = WT + 1048576;
    short* On  = (short*)(ws + OFF_ON);
    float* mlp = (float*)(ws + OFF_ML);
    float* kbp = (float*)(ws + OFF_KB);
    float* ap  = (float*)(ws + OFF_AP);

    // 1. fused prep: LN(q,k,v) + weight transposes + kbias
    prep_all<<<4657, 256, 0, stream>>>(query, key, value, qg, qb, kg, kb, vg, vb,
                                       Wq, Wk, Wv, Wo, gW, kmask,
                                       qn, kn, vn, WT, kbp);

    // 2. fused QKV projection, 64x64 tiles (194 Mtiles x 8 Ntiles)
    gemm64<0,512><<<1552, 256, 0, stream>>>(qn, nullptr, nullptr, WT, qh, khp, vhp,
                                            nullptr, nullptr, nullptr, nullptr, nullptr);

    // 3. V transpose for PV MFMA B-operand
    transpose_v<<<528, 256, 0, stream>>>(vhp, vhT);

    // 4. flash attention, split-KV 3-way, XCD-local heads, LDS-staged K/V
    flash_kernel<<<1536, 256, 0, stream>>>(qh, khp, vhT, kbp, On, mlp);

    // 5. output projection with fused split-KV merge (f32 out)
    gemm64<1,512><<<512, 256, 0, stream>>>(nullptr, nullptr, nullptr, WoT, nullptr, nullptr, nullptr,
                                           ap, nullptr, On, mlp, qmask);

    // 6. gate GEMM fused: concat-stage + sigmoid + residual
    gemm64<2,1024><<<512, 256, 0, stream>>>(nullptr, query, ap, gWT, nullptr, nullptr, nullptr,
                                            out, gB, nullptr, nullptr, nullptr);

    (void)in_sizes; (void)n_in; (void)out_size;
}

// Round 10
// 223.022 us; speedup vs baseline: 1.4718x; 1.0375x over previous
//
#include <hip/hip_runtime.h>

typedef float f32x4 __attribute__((ext_vector_type(4)));
typedef short s16x8 __attribute__((ext_vector_type(8)));

#define DEV __device__ __forceinline__

DEV short f2bf(float f) {
    union { float f; unsigned u; } v; v.f = f;
    unsigned r = v.u + 0x7fffu + ((v.u >> 16) & 1u);
    return (short)(r >> 16);
}
DEV float bf2f(short s) {
    union { unsigned u; float f; } v; v.u = ((unsigned)(unsigned short)s) << 16;
    return v.f;
}

// B=2, Q=K=2048, D=512, H=8, hd=64. KV padded: 2048 real + 1 zero-attn + 31 pad = 2080.
// kn/vn padded to 4224 rows (multiple of 128, zero-filled) for 128-row GEMM tiles.
#define SEQ    2048
#define DMODEL 512
#define KPAD   2080
#define NROWS  32768   /* B*H*SEQ flash output rows */

// ws layout (bytes) — identical to the round-7 layout that passed.
#define OFF_QN   0ull            /* 4096 rows  = 4,194,304 */
#define OFF_KN   4194304ull      /* 4224 rows  = 4,325,376 */
#define OFF_VN   8519680ull      /* 4224 rows  -> ends 12,845,056 */
#define OFF_QH   12845056ull     /* 4,194,304 */
#define OFF_KH   17039360ull     /* 4160 rows = 4,259,840 -> ends 21,299,200 */
#define OFF_VH   21364736ull     /* vhp 4,259,840 -> ends 25,624,576 */
#define OFF_VHT  25690112ull     /* 4,259,840 -> ends 29,949,952 */
#define OFF_AV   29949952ull     /* 4,194,304 */
#define OFF_WQT  34144256ull     /* WqT|WkT|WvT|WoT|gWT = 4*524,288 + 1,048,576 */
#define WS_NEEDED 37289984ull
// aliased (lifetimes disjoint; proven in r7):
#define OFF_ON   0ull            /* flash partials bf16 [3][32768][64] = 12,582,912 over qn|kn|vn (dead post-qkv) */
#define OFF_ML   21364736ull     /* (m,l) f32 [3][32768][2] over vhp (dead post-transpose; merge reads before ap write) */
#define OFF_KB   29949952ull     /* key bias f32 2*2080*4 over av region (flash reads before merge writes av) */
#define OFF_AP   17039360ull     /* attn_proj f32 8,388,608 over kh+vhp (dead post-flash/merge) */

// ---------------------------------------------------------------- fused prep: LN(q,k,v) + weight transpose + kbias
// bid 0..3135: layernorm rows (kn/vn padded to 4224); 3136..4671: weight tiles; 4672..4688: kbias
__global__ __launch_bounds__(256) void prep_all(
    const float* __restrict__ q, const float* __restrict__ k, const float* __restrict__ v,
    const float* __restrict__ qg, const float* __restrict__ qb,
    const float* __restrict__ kg, const float* __restrict__ kb2,
    const float* __restrict__ vg, const float* __restrict__ vb,
    const float* __restrict__ Wq, const float* __restrict__ Wk,
    const float* __restrict__ Wv, const float* __restrict__ Wo,
    const float* __restrict__ gW, const int* __restrict__ km,
    short* __restrict__ qn, short* __restrict__ kn, short* __restrict__ vn,
    short* __restrict__ WT, float* __restrict__ kbias)
{
    int bid = blockIdx.x;
    if (bid < 3136) {
        const float *in, *gamma, *beta; short* out; int Spad;
        if (bid < 1024)      { in=q; gamma=qg; beta=qb;  out=qn; Spad=SEQ;  }
        else if (bid < 2080) { bid-=1024; in=k; gamma=kg; beta=kb2; out=kn; Spad=KPAD; }
        else                 { bid-=2080; in=v; gamma=vg; beta=vb;  out=vn; Spad=KPAD; }

        int w = threadIdx.x >> 6, l = threadIdx.x & 63;
        int r = bid * 4 + w;
        short* op = out + (size_t)r * DMODEL + l * 8;
        s16x8 o = {0,0,0,0,0,0,0,0};
        if (r >= 2 * Spad) { *(s16x8*)op = o; return; }   // zero pad rows (4160..4223)
        int b = r / Spad, j = r - b * Spad;
        if (j >= SEQ) {
            if (j == SEQ) {
                f32x4 b0 = *(const f32x4*)(beta + l*8);
                f32x4 b1 = *(const f32x4*)(beta + l*8 + 4);
                #pragma unroll
                for (int t=0;t<4;t++){ o[t]=f2bf(b0[t]); o[t+4]=f2bf(b1[t]); }
            }
            *(s16x8*)op = o; return;
        }
        const float* ip = in + ((size_t)b * SEQ + j) * DMODEL + l * 8;
        f32x4 x0 = *(const f32x4*)ip;
        f32x4 x1 = *(const f32x4*)(ip + 4);
        float s = x0[0]+x0[1]+x0[2]+x0[3]+x1[0]+x1[1]+x1[2]+x1[3];
        #pragma unroll
        for (int off=1; off<64; off<<=1) s += __shfl_xor(s, off);
        float mean = s * (1.0f/512.0f);
        float vs = 0.f;
        #pragma unroll
        for (int t=0;t<4;t++){ float d0=x0[t]-mean, d1=x1[t]-mean; vs += d0*d0 + d1*d1; }
        #pragma unroll
        for (int off=1; off<64; off<<=1) vs += __shfl_xor(vs, off);
        float rstd = rsqrtf(vs * (1.0f/512.0f) + 1e-5f);
        f32x4 g0 = *(const f32x4*)(gamma + l*8), g1 = *(const f32x4*)(gamma + l*8 + 4);
        f32x4 b0 = *(const f32x4*)(beta + l*8),  b1 = *(const f32x4*)(beta + l*8 + 4);
        #pragma unroll
        for (int t=0;t<4;t++){
            o[t]   = f2bf((x0[t]-mean)*rstd*g0[t] + b0[t]);
            o[t+4] = f2bf((x1[t]-mean)*rstd*g1[t] + b1[t]);
        }
        *(s16x8*)op = o;
        return;
    }
    bid -= 3136;
    if (bid >= 1536) {
        int i = (bid - 1536) * 256 + threadIdx.x;
        if (i >= 2 * KPAD) return;
        int b = i / KPAD, j = i - b * KPAD;
        float val;
        if (j < SEQ)       val = km[b*SEQ + j] ? 0.0f : -1e30f;
        else if (j == SEQ) val = 0.0f;     // zero-attn slot (mask bit 1)
        else               val = -1e30f;   // pad rows
        kbias[i] = val;
        return;
    }
    const float* in; short* out; int K;
    if (bid < 1024) {
        int wsel = bid >> 8;
        in = (wsel==0) ? Wq : (wsel==1) ? Wk : (wsel==2) ? Wv : Wo;
        out = WT + (size_t)wsel * 262144;
        K = 512; bid &= 255;
    } else {
        in = gW; out = WT + 1048576; K = 1024; bid -= 1024;
    }
    __shared__ float t[32][33];
    int bx = bid & 15, by = bid >> 4;
    int n0 = bx * 32, k0 = by * 32;
    int tx = threadIdx.x & 31, ty = threadIdx.x >> 5;
    #pragma unroll
    for (int i=0;i<4;i++)
        t[ty + i*8][tx] = in[(size_t)(k0 + ty + i*8) * 512 + n0 + tx];
    __syncthreads();
    #pragma unroll
    for (int i=0;i<4;i++)
        out[(size_t)(n0 + ty + i*8) * K + k0 + tx] = f2bf(t[tx][ty + i*8]);
}

// ---------------------------------------------------------------- 128x128-tile QKV GEMM (m97 structure)
// A = qn|kn|vn (12544,512) bf16; B seg by M-tile (tm<32 Wq | tm<65 Wk | else Wv).
// 4 waves (2x2 quadrants of 64x64), acc 4x4, BK=64 -> 32 MFMA/K-step/wave.
__global__ __launch_bounds__(256) void gemm128_qkv(
    const short* __restrict__ A, const short* __restrict__ WT,
    short* __restrict__ qh, short* __restrict__ khp, short* __restrict__ vhp)
{
    __shared__ short As[128*64];
    __shared__ short Bs[128*64];
    int tid = threadIdx.x;
    int w = tid >> 6, l = tid & 63;
    int lr = l & 15, lg = l >> 4;
    int tm = blockIdx.x >> 2, tn = blockIdx.x & 3;
    int seg = (tm < 32) ? 0 : (tm < 65) ? 1 : 2;   // 4096 | 8320 row boundaries
    const short* Bt = WT + (size_t)seg * 262144;
    int wm = w >> 1, wn = w & 1;
    int srow = tid >> 3, sslot = tid & 7;

    f32x4 acc[4][4];
    #pragma unroll
    for (int m=0;m<4;m++)
        #pragma unroll
        for (int n=0;n<4;n++) acc[m][n] = (f32x4){0.f,0.f,0.f,0.f};

    for (int k0 = 0; k0 < 512; k0 += 64) {
        #pragma unroll
        for (int i=0;i<4;i++){
            int row = i*32 + srow;
            int gslot = sslot ^ (row & 7);
            const short* ga = A  + (size_t)(tm*128 + row) * 512 + k0 + gslot*8;
            const short* gb = Bt + (size_t)(tn*128 + row) * 512 + k0 + gslot*8;
            short* la = As + (i*32 + w*8) * 64;
            short* lb = Bs + (i*32 + w*8) * 64;
            __builtin_amdgcn_global_load_lds((const __attribute__((address_space(1))) void*)ga,
                                             (__attribute__((address_space(3))) void*)la, 16, 0, 0);
            __builtin_amdgcn_global_load_lds((const __attribute__((address_space(1))) void*)gb,
                                             (__attribute__((address_space(3))) void*)lb, 16, 0, 0);
        }
        __syncthreads();
        #pragma unroll
        for (int s=0;s<2;s++){
            s16x8 af[4], bfr[4];
            #pragma unroll
            for (int m=0;m<4;m++){
                int row = wm*64 + m*16 + lr;
                int slot = (s*4 + lg) ^ (row & 7);
                af[m] = *(const s16x8*)(As + row*64 + slot*8);
            }
            #pragma unroll
            for (int n=0;n<4;n++){
                int row = wn*64 + n*16 + lr;
                int slot = (s*4 + lg) ^ (row & 7);
                bfr[n] = *(const s16x8*)(Bs + row*64 + slot*8);
            }
            #pragma unroll
            for (int m=0;m<4;m++)
                #pragma unroll
                for (int n=0;n<4;n++)
                    acc[m][n] = __builtin_amdgcn_mfma_f32_16x16x32_bf16(af[m], bfr[n], acc[m][n], 0, 0, 0);
        }
        __syncthreads();
    }

    int rb = tm*128 + wm*64;
    int cb = tn*128 + wn*64;
    #pragma unroll
    for (int n=0;n<4;n++){
        int col = cb + n*16 + lr;
        #pragma unroll
        for (int m=0;m<4;m++){
            #pragma unroll
            for (int j=0;j<4;j++){
                int row = rb + m*16 + lg*4 + j;
                short bv = f2bf(acc[m][n][j]);
                if (row < 4096) {
                    qh[(size_t)row*512 + col] = bv;
                } else if (row < 8320) {
                    int r2 = row - 4096;
                    if (r2 < 4160) khp[(size_t)r2*512 + col] = bv;
                } else {
                    int r2 = row - 8320;
                    if (r2 < 4160) vhp[(size_t)r2*512 + col] = bv;
                }
            }
        }
    }
}

// ---------------------------------------------------------------- 64x64-tile GEMM (wo / gate)
// MODE 1: Wo — A bf16 (av) via global_load_lds, f32 out.
// MODE 2: gate — A = concat(query, ap) f32 staged->bf16, sigmoid-gate+residual epilogue.
template<int MODE, int KK>
__global__ __launch_bounds__(256) void gemm64(
    const short* __restrict__ A, const float* __restrict__ F1, const float* __restrict__ F2,
    const short* __restrict__ WT,
    float* __restrict__ FO, const float* __restrict__ bias)
{
    __shared__ short As[64*64];
    __shared__ short Bs[64*64];
    int tid = threadIdx.x;
    int w = tid >> 6, l = tid & 63;
    int lr = l & 15, lg = l >> 4;
    int tm = blockIdx.x >> 3, tn = blockIdx.x & 7;
    int wm = w >> 1, wn = w & 1;
    int srow = tid >> 3, sslot = tid & 7;

    f32x4 acc[2][2];
    #pragma unroll
    for (int m=0;m<2;m++)
        #pragma unroll
        for (int n=0;n<2;n++) acc[m][n] = (f32x4){0.f,0.f,0.f,0.f};

    for (int k0 = 0; k0 < KK; k0 += 64) {
        #pragma unroll
        for (int i=0;i<2;i++){
            int row = i*32 + srow;
            int gslot = sslot ^ (row & 7);
            const short* gb = WT + (size_t)(tn*64 + row) * KK + k0 + gslot*8;
            short* lb = Bs + (i*256 + w*64) * 8;
            __builtin_amdgcn_global_load_lds((const __attribute__((address_space(1))) void*)gb,
                                             (__attribute__((address_space(3))) void*)lb, 16, 0, 0);
        }
        if (MODE == 1) {
            #pragma unroll
            for (int i=0;i<2;i++){
                int row = i*32 + srow;
                int gslot = sslot ^ (row & 7);
                const short* ga = A + (size_t)(tm*64 + row) * KK + k0 + gslot*8;
                short* la = As + (i*256 + w*64) * 8;
                __builtin_amdgcn_global_load_lds((const __attribute__((address_space(1))) void*)ga,
                                                 (__attribute__((address_space(3))) void*)la, 16, 0, 0);
            }
        } else {
            const float* src = (k0 < 512) ? F1 : F2;
            int csub = (k0 < 512) ? k0 : k0 - 512;
            #pragma unroll
            for (int i=0;i<2;i++){
                int row = i*32 + srow;
                const float* gp = src + (size_t)(tm*64 + row) * 512 + csub + sslot*8;
                f32x4 a0 = *(const f32x4*)gp;
                f32x4 a1 = *(const f32x4*)(gp + 4);
                s16x8 o;
                #pragma unroll
                for (int t=0;t<4;t++){ o[t] = f2bf(a0[t]); o[t+4] = f2bf(a1[t]); }
                *(s16x8*)(As + row*64 + (sslot ^ (row & 7))*8) = o;
            }
        }
        __syncthreads();
        #pragma unroll
        for (int s=0;s<2;s++){
            s16x8 af[2], bfr[2];
            #pragma unroll
            for (int m=0;m<2;m++){
                int row = wm*32 + m*16 + lr;
                int slot = (s*4 + lg) ^ (row & 7);
                af[m] = *(const s16x8*)(As + row*64 + slot*8);
            }
            #pragma unroll
            for (int n=0;n<2;n++){
                int row = wn*32 + n*16 + lr;
                int slot = (s*4 + lg) ^ (row & 7);
                bfr[n] = *(const s16x8*)(Bs + row*64 + slot*8);
            }
            #pragma unroll
            for (int m=0;m<2;m++)
                #pragma unroll
                for (int n=0;n<2;n++)
                    acc[m][n] = __builtin_amdgcn_mfma_f32_16x16x32_bf16(af[m], bfr[n], acc[m][n], 0, 0, 0);
        }
        __syncthreads();
    }

    #pragma unroll
    for (int n=0;n<2;n++){
        int col = tn*64 + wn*32 + n*16 + lr;
        float badd = (MODE == 2) ? bias[col] : 0.0f;
        #pragma unroll
        for (int m=0;m<2;m++){
            #pragma unroll
            for (int j=0;j<4;j++){
                int row = tm*64 + wm*32 + m*16 + lg*4 + j;
                float v = acc[m][n][j];
                if (MODE == 1) {
                    FO[(size_t)row*512 + col] = v;
                } else {
                    size_t idx = (size_t)row*512 + col;
                    float g = 1.0f / (1.0f + __expf(-(v + badd)));
                    float qv = F1[idx], a = F2[idx];
                    FO[idx] = qv + g*qv + (1.0f - g)*a;
                }
            }
        }
    }
}

// ---------------------------------------------------------------- vhp -> vhT[b][h][64][KPAD]
__global__ __launch_bounds__(256) void transpose_v(
    const short* __restrict__ vh, short* __restrict__ vhT)
{
    __shared__ short t[64][72];
    int tid = threadIdx.x, bid = blockIdx.x;
    int kt = bid % 33; int hh = (bid / 33) & 7; int b = bid / (33*8);
    int k0 = kt * 64;
    int rr = tid >> 3, c8 = (tid & 7) * 8;
    #pragma unroll
    for (int p=0;p<2;p++){
        int kr = p*32 + rr;
        int gk = k0 + kr;
        s16x8 v = {0,0,0,0,0,0,0,0};
        if (gk < KPAD) v = *(const s16x8*)(vh + (size_t)(b*KPAD + gk)*DMODEL + hh*64 + c8);
        *(s16x8*)&t[kr][c8] = v;
    }
    __syncthreads();
    #pragma unroll
    for (int p=0;p<2;p++){
        int dr = p*32 + rr;
        if (k0 + c8 < KPAD){
            s16x8 o;
            #pragma unroll
            for (int j2=0;j2<8;j2++) o[j2] = t[c8+j2][dr];
            *(s16x8*)(vhT + ((size_t)(b*8 + hh)*64 + dr)*KPAD + k0 + c8) = o;
        }
    }
}

// ---------------------------------------------------------------- flash attention, split-KV 3-way
// bid%8 == h: each XCD owns one head. Block-cooperative LDS staging of K/V (r8, verified).
__global__ __launch_bounds__(256, 6) void flash_kernel(
    const short* __restrict__ qh, const short* __restrict__ kh,
    const short* __restrict__ vhT, const float* __restrict__ kbias,
    short* __restrict__ On, float* __restrict__ ml)
{
    __shared__ short Ks[64*64];
    __shared__ short Vs[64*64];
    __shared__ short plds[4][16*72];
    int tid = threadIdx.x;
    int w = tid >> 6, l = tid & 63;
    int bid = blockIdx.x;
    int h = bid & 7;
    int b = (bid >> 3) & 1;
    int t = bid >> 4;            // 0..95
    int qblk = t / 3;
    int split = t - qblk * 3;
    int q0 = qblk * 64 + w * 16;
    int cl = l & 15, rg = l >> 4;
    int srow = tid >> 3, sslot = tid & 7;

    const short* qp = qh + ((size_t)(b*SEQ + q0 + cl))*DMODEL + h*64 + rg*8;
    s16x8 qf0 = *(const s16x8*)qp;
    s16x8 qf1 = *(const s16x8*)(qp + 32);

    f32x4 O[4];
    float mrow[4], lsum[4];
    #pragma unroll
    for (int n=0;n<4;n++) O[n] = (f32x4){0.f,0.f,0.f,0.f};
    #pragma unroll
    for (int j=0;j<4;j++){ mrow[j] = -1e30f; lsum[j] = 0.f; }

    const short* khb = kh + (size_t)b*KPAD*DMODEL + h*64;
    const short* vtb = vhT + (size_t)(b*8 + h)*64*KPAD;
    const float* kbb = kbias + b*KPAD;
    short* pl = plds[w];

    int kc0 = split * 11;
    int kcN = kc0 + ((split == 2) ? 10 : 11);
    for (int kc = kc0; kc < kcN; ++kc) {
        int k0 = kc * 64;
        if (kc > kc0) __syncthreads();
        #pragma unroll
        for (int i=0;i<2;i++){
            int row = i*32 + srow;
            int gslot = sslot ^ (row & 7);
            const short* gk = khb + (size_t)(k0 + row)*DMODEL + gslot*8;
            const short* gv = vtb + (size_t)row*KPAD + k0 + gslot*8;
            short* lk = Ks + (i*256 + w*64)*8;
            short* lv = Vs + (i*256 + w*64)*8;
            __builtin_amdgcn_global_load_lds((const __attribute__((address_space(1))) void*)gk,
                                             (__attribute__((address_space(3))) void*)lk, 16, 0, 0);
            __builtin_amdgcn_global_load_lds((const __attribute__((address_space(1))) void*)gv,
                                             (__attribute__((address_space(3))) void*)lv, 16, 0, 0);
        }
        __syncthreads();

        float sv[4][4];
        #pragma unroll
        for (int nh=0; nh<4; ++nh) {
            int row = nh*16 + cl;
            s16x8 ka  = *(const s16x8*)(Ks + row*64 + ((rg)     ^ (row & 7))*8);
            s16x8 kb2 = *(const s16x8*)(Ks + row*64 + ((4 + rg) ^ (row & 7))*8);
            f32x4 z = (f32x4){0.f,0.f,0.f,0.f};
            z = __builtin_amdgcn_mfma_f32_16x16x32_bf16(qf0, ka,  z, 0, 0, 0);
            z = __builtin_amdgcn_mfma_f32_16x16x32_bf16(qf1, kb2, z, 0, 0, 0);
            float bias = kbb[k0 + nh*16 + cl];
            #pragma unroll
            for (int j=0;j<4;j++) sv[nh][j] = fmaf(z[j], 0.125f, bias);
        }
        float ml4[4];
        #pragma unroll
        for (int j=0;j<4;j++)
            ml4[j] = fmaxf(fmaxf(sv[0][j], sv[1][j]), fmaxf(sv[2][j], sv[3][j]));
        #pragma unroll
        for (int off=1; off<16; off<<=1){
            #pragma unroll
            for (int j=0;j<4;j++) ml4[j] = fmaxf(ml4[j], __shfl_xor(ml4[j], off));
        }
        bool need = (ml4[0] > mrow[0]+8.f) || (ml4[1] > mrow[1]+8.f) ||
                    (ml4[2] > mrow[2]+8.f) || (ml4[3] > mrow[3]+8.f);
        if (__any(need)) {
            #pragma unroll
            for (int j=0;j<4;j++){
                float mn = fmaxf(mrow[j], ml4[j]);
                float sc = __expf(mrow[j] - mn);
                mrow[j] = mn; lsum[j] *= sc;
                #pragma unroll
                for (int n=0;n<4;n++) O[n][j] *= sc;
            }
        }
        float ps[4] = {0.f,0.f,0.f,0.f};
        #pragma unroll
        for (int nh=0; nh<4; ++nh){
            #pragma unroll
            for (int j=0;j<4;j++){
                float p = __expf(sv[nh][j] - mrow[j]);
                ps[j] += p;
                pl[(rg*4 + j)*72 + nh*16 + cl] = f2bf(p);
            }
        }
        #pragma unroll
        for (int off=1; off<16; off<<=1){
            #pragma unroll
            for (int j=0;j<4;j++) ps[j] += __shfl_xor(ps[j], off);
        }
        #pragma unroll
        for (int j=0;j<4;j++) lsum[j] += ps[j];

        s16x8 pa0 = *(const s16x8*)(pl + cl*72 + rg*8);
        s16x8 pa1 = *(const s16x8*)(pl + cl*72 + 32 + rg*8);
        __builtin_amdgcn_s_setprio(1);
        #pragma unroll
        for (int n=0;n<4;n++){
            int row = n*16 + cl;
            s16x8 vf0 = *(const s16x8*)(Vs + row*64 + ((rg)     ^ (row & 7))*8);
            s16x8 vf1 = *(const s16x8*)(Vs + row*64 + ((4 + rg) ^ (row & 7))*8);
            O[n] = __builtin_amdgcn_mfma_f32_16x16x32_bf16(pa0, vf0, O[n], 0, 0, 0);
            O[n] = __builtin_amdgcn_mfma_f32_16x16x32_bf16(pa1, vf1, O[n], 0, 0, 0);
        }
        __builtin_amdgcn_s_setprio(0);
    }

    if (split == 2) {  // tail: keys 2048..2079, global-direct
        int k0 = 2048;
        float sv[2][4];
        #pragma unroll
        for (int nh=0; nh<2; ++nh) {
            const short* kp = khb + (size_t)(k0 + nh*16 + cl)*DMODEL + rg*8;
            s16x8 ka = *(const s16x8*)kp;
            s16x8 kb2 = *(const s16x8*)(kp + 32);
            f32x4 z = (f32x4){0.f,0.f,0.f,0.f};
            z = __builtin_amdgcn_mfma_f32_16x16x32_bf16(qf0, ka,  z, 0, 0, 0);
            z = __builtin_amdgcn_mfma_f32_16x16x32_bf16(qf1, kb2, z, 0, 0, 0);
            float bias = kbb[k0 + nh*16 + cl];
            #pragma unroll
            for (int j=0;j<4;j++) sv[nh][j] = fmaf(z[j], 0.125f, bias);
        }
        float ml4[4];
        #pragma unroll
        for (int j=0;j<4;j++) ml4[j] = fmaxf(sv[0][j], sv[1][j]);
        #pragma unroll
        for (int off=1; off<16; off<<=1){
            #pragma unroll
            for (int j=0;j<4;j++) ml4[j] = fmaxf(ml4[j], __shfl_xor(ml4[j], off));
        }
        bool need = (ml4[0] > mrow[0]+8.f) || (ml4[1] > mrow[1]+8.f) ||
                    (ml4[2] > mrow[2]+8.f) || (ml4[3] > mrow[3]+8.f);
        if (__any(need)) {
            #pragma unroll
            for (int j=0;j<4;j++){
                float mn = fmaxf(mrow[j], ml4[j]);
                float sc = __expf(mrow[j] - mn);
                mrow[j] = mn; lsum[j] *= sc;
                #pragma unroll
                for (int n=0;n<4;n++) O[n][j] *= sc;
            }
        }
        float ps[4] = {0.f,0.f,0.f,0.f};
        #pragma unroll
        for (int nh=0; nh<2; ++nh){
            #pragma unroll
            for (int j=0;j<4;j++){
                float p = __expf(sv[nh][j] - mrow[j]);
                ps[j] += p;
                pl[(rg*4 + j)*72 + nh*16 + cl] = f2bf(p);
            }
        }
        #pragma unroll
        for (int off=1; off<16; off<<=1){
            #pragma unroll
            for (int j=0;j<4;j++) ps[j] += __shfl_xor(ps[j], off);
        }
        #pragma unroll
        for (int j=0;j<4;j++) lsum[j] += ps[j];

        s16x8 pa0 = *(const s16x8*)(pl + cl*72 + rg*8);
        __builtin_amdgcn_s_setprio(1);
        #pragma unroll
        for (int n=0;n<4;n++){
            s16x8 vf0 = *(const s16x8*)(vtb + (size_t)(n*16 + cl)*KPAD + k0 + rg*8);
            O[n] = __builtin_amdgcn_mfma_f32_16x16x32_bf16(pa0, vf0, O[n], 0, 0, 0);
        }
        __builtin_amdgcn_s_setprio(0);
    }

    // store normalized partial + (m, l)
    int rbase = ((b*8 + h) << 11) + q0;
    #pragma unroll
    for (int j=0;j<4;j++){
        int r = rbase + rg*4 + j;
        float invl = 1.0f / lsum[j];
        #pragma unroll
        for (int n=0;n<4;n++)
            On[((size_t)split*NROWS + r)*64 + n*16 + cl] = f2bf(O[n][j] * invl);
        if (cl == 0){
            ml[((size_t)split*NROWS + r)*2    ] = mrow[j];
            ml[((size_t)split*NROWS + r)*2 + 1] = lsum[j];
        }
    }
}

// ---------------------------------------------------------------- merge 3 split-KV partials -> av bf16
__global__ __launch_bounds__(256) void merge_kernel(
    const short* __restrict__ On, const float* __restrict__ ml,
    const int* __restrict__ qmask, short* __restrict__ av)
{
    int tid = threadIdx.x;
    int r = blockIdx.x * 32 + (tid >> 3);
    int d8 = (tid & 7) * 8;
    float m0 = ml[(size_t)r*2],              l0 = ml[(size_t)r*2 + 1];
    float m1 = ml[((size_t)NROWS + r)*2],    l1 = ml[((size_t)NROWS + r)*2 + 1];
    float m2 = ml[((size_t)2*NROWS + r)*2],  l2 = ml[((size_t)2*NROWS + r)*2 + 1];
    float m = fmaxf(m0, fmaxf(m1, m2));
    float w0 = l0 * __expf(m0 - m), w1 = l1 * __expf(m1 - m), w2 = l2 * __expf(m2 - m);
    int qrow = r & 2047, bh = r >> 11, h = bh & 7, b = bh >> 3;
    int qm = qmask[b*SEQ + qrow];
    float inv = qm ? 1.0f / (w0 + w1 + w2) : 0.0f;
    w0 *= inv; w1 *= inv; w2 *= inv;
    s16x8 o0 = *(const s16x8*)(On + (size_t)r*64 + d8);
    s16x8 o1 = *(const s16x8*)(On + ((size_t)NROWS + r)*64 + d8);
    s16x8 o2 = *(const s16x8*)(On + ((size_t)2*NROWS + r)*64 + d8);
    s16x8 o;
    #pragma unroll
    for (int e=0;e<8;e++) o[e] = f2bf(w0*bf2f(o0[e]) + w1*bf2f(o1[e]) + w2*bf2f(o2[e]));
    *(s16x8*)(av + ((size_t)(b*SEQ + qrow))*DMODEL + h*64 + d8) = o;
}

// ---------------------------------------------------------------- launch
extern "C" void kernel_launch(void* const* d_in, const int* in_sizes, int n_in,
                              void* d_out, int out_size, void* d_ws, size_t ws_size,
                              hipStream_t stream)
{
    const float* query = (const float*)d_in[0];
    const float* key   = (const float*)d_in[1];
    const float* value = (const float*)d_in[2];
    const float* Wq    = (const float*)d_in[3];
    const float* Wk    = (const float*)d_in[4];
    const float* Wv    = (const float*)d_in[5];
    const float* Wo    = (const float*)d_in[6];
    const float* gW    = (const float*)d_in[7];
    const float* gB    = (const float*)d_in[8];
    const float* qg    = (const float*)d_in[9];
    const float* qb    = (const float*)d_in[10];
    const float* kg    = (const float*)d_in[11];
    const float* kb    = (const float*)d_in[12];
    const float* vg    = (const float*)d_in[13];
    const float* vb    = (const float*)d_in[14];
    const int* qmask   = (const int*)d_in[15];
    const int* kmask   = (const int*)d_in[16];
    float* out = (float*)d_out;
    char* ws = (char*)d_ws;

    if (ws_size < WS_NEEDED) return;

    short* qn  = (short*)(ws + OFF_QN);
    short* kn  = (short*)(ws + OFF_KN);
    short* vn  = (short*)(ws + OFF_VN);
    short* qh  = (short*)(ws + OFF_QH);
    short* khp = (short*)(ws + OFF_KH);
    short* vhp = (short*)(ws + OFF_VH);
    short* vhT = (short*)(ws + OFF_VHT);
    short* av  = (short*)(ws + OFF_AV);
    short* WT  = (short*)(ws + OFF_WQT);
    short* WoT = WT + 3*262144;
    short* gWT = WT + 1048576;
    short* On  = (short*)(ws + OFF_ON);
    float* mlp = (float*)(ws + OFF_ML);
    float* kbp = (float*)(ws + OFF_KB);
    float* ap  = (float*)(ws + OFF_AP);

    // 1. fused prep: LN(q,k,v; kn/vn zero-padded to 4224 rows) + weight transposes + kbias
    prep_all<<<4689, 256, 0, stream>>>(query, key, value, qg, qb, kg, kb, vg, vb,
                                       Wq, Wk, Wv, Wo, gW, kmask,
                                       qn, kn, vn, WT, kbp);

    // 2. fused QKV projection, 128x128 tiles (98 Mtiles x 4 Ntiles)
    gemm128_qkv<<<392, 256, 0, stream>>>(qn, WT, qh, khp, vhp);

    // 3. V transpose for PV MFMA B-operand
    transpose_v<<<528, 256, 0, stream>>>(vhp, vhT);

    // 4. flash attention, split-KV 3-way, XCD-local heads, LDS-staged K/V
    flash_kernel<<<1536, 256, 0, stream>>>(qh, khp, vhT, kbp, On, mlp);

    // 5. merge split-KV partials -> av (kbias dead; av overlays it)
    merge_kernel<<<1024, 256, 0, stream>>>(On, mlp, qmask, av);

    // 6. output projection (f32 out)
    gemm64<1,512><<<512, 256, 0, stream>>>(av, nullptr, nullptr, WoT, ap, nullptr);

    // 7. gate GEMM fused: concat-stage + sigmoid + residual
    gemm64<2,1024><<<512, 256, 0, stream>>>(nullptr, query, ap, gWT, out, gB);

    (void)in_sizes; (void)n_in; (void)out_size;
}